// Round 7
// baseline (251.613 us; speedup 1.0000x reference)
//
#include <hip/hip_runtime.h>

#define D 64
#define SCAN_CHUNK 1024   // elements per scan1 block (256 thr x 4)

__device__ __forceinline__ unsigned int bf16r(float f) {
    unsigned int u = __float_as_uint(f);
    return (u + 0x7fffu + ((u >> 16) & 1u)) >> 16;   // RNE to bf16
}
__device__ __forceinline__ float bflo(unsigned int u) { return __uint_as_float(u << 16); }
__device__ __forceinline__ float bfhi(unsigned int u) { return __uint_as_float(u & 0xffff0000u); }

// ---------------- f32 -> bf16 row conversion (8 elems/thread) --------------
__global__ __launch_bounds__(256) void cvt_kernel(
    const float* __restrict__ in, unsigned short* __restrict__ out, int n8)
{
    int t = blockIdx.x * 256 + threadIdx.x;
    if (t >= n8) return;
    const float4* p = reinterpret_cast<const float4*>(in) + (size_t)t * 2;
    float4 v0 = p[0], v1 = p[1];
    uint4 o;
    o.x = bf16r(v0.x) | (bf16r(v0.y) << 16);
    o.y = bf16r(v0.z) | (bf16r(v0.w) << 16);
    o.z = bf16r(v1.x) | (bf16r(v1.y) << 16);
    o.w = bf16r(v1.z) | (bf16r(v1.w) << 16);
    reinterpret_cast<uint4*>(out)[t] = o;
}

// ---------------- tap0 (f32 in): y[row][j] = sum_i x[row][i]*W[j][i]+b[j] --
__global__ __launch_bounds__(256) void tap_kernel(
    const float* __restrict__ xin, const float* __restrict__ W,
    const float* __restrict__ b, float* __restrict__ y,
    int n_nodes, int first)
{
    __shared__ float Wt[D * (D + 1)];
    __shared__ float bs[D];
    __shared__ float xs[4][D];

    int tid = threadIdx.x;
    for (int t = tid; t < D * D; t += 256) {
        int j = t >> 6, i = t & 63;
        Wt[i * (D + 1) + j] = W[t];
    }
    if (tid < D) bs[tid] = b[tid];

    int rl = tid >> 6;
    int j  = tid & 63;
    int row = blockIdx.x * 4 + rl;
    if (row < n_nodes) xs[rl][j] = xin[(size_t)row * D + j];
    __syncthreads();

    if (row >= n_nodes) return;

    float acc = bs[j];
    #pragma unroll 8
    for (int i = 0; i < D; ++i)
        acc = fmaf(xs[rl][i], Wt[i * (D + 1) + j], acc);

    float* yp = y + (size_t)row * D + j;
    *yp = first ? acc : (*yp + acc);
}

// ---------------- tap (bf16 in): y[row][j] += sum_i xb[row][i]*W[j][i]+b[j]
__global__ __launch_bounds__(256) void tap_bf16_kernel(
    const unsigned short* __restrict__ xin, const float* __restrict__ W,
    const float* __restrict__ b, float* __restrict__ y, int n_nodes)
{
    __shared__ float Wt[D * (D + 1)];
    __shared__ float bs[D];
    __shared__ float xs[4][D];

    int tid = threadIdx.x;
    for (int t = tid; t < D * D; t += 256) {
        int j = t >> 6, i = t & 63;
        Wt[i * (D + 1) + j] = W[t];
    }
    if (tid < D) bs[tid] = b[tid];

    int rl = tid >> 6;
    int lane = tid & 63;
    int row = blockIdx.x * 4 + rl;
    if (row < n_nodes && lane < 32) {
        unsigned int u = reinterpret_cast<const unsigned int*>(xin + (size_t)row * D)[lane];
        xs[rl][2 * lane]     = bflo(u);
        xs[rl][2 * lane + 1] = bfhi(u);
    }
    __syncthreads();

    if (row >= n_nodes) return;

    float acc = bs[lane];
    #pragma unroll 8
    for (int i = 0; i < D; ++i)
        acc = fmaf(xs[rl][i], Wt[i * (D + 1) + lane], acc);

    y[(size_t)row * D + lane] += acc;
}

// ---------------- CSR build ------------------------------------------------
__global__ __launch_bounds__(256) void hist_loc_kernel(
    const int* __restrict__ dst, int* __restrict__ counts,
    int* __restrict__ loc, int n_edges)
{
    int t = blockIdx.x * 256 + threadIdx.x;
    int e4 = t * 4;
    if (e4 + 4 <= n_edges) {
        int4 d = *reinterpret_cast<const int4*>(dst + e4);
        int4 l;
        l.x = atomicAdd(&counts[d.x], 1);
        l.y = atomicAdd(&counts[d.y], 1);
        l.z = atomicAdd(&counts[d.z], 1);
        l.w = atomicAdd(&counts[d.w], 1);
        *reinterpret_cast<int4*>(loc + e4) = l;
    } else {
        for (int e = e4; e < n_edges; ++e)
            loc[e] = atomicAdd(&counts[dst[e]], 1);
    }
}

__global__ __launch_bounds__(256) void scan1_kernel(
    const int* __restrict__ counts, int* __restrict__ excl,
    int* __restrict__ bsum, int n)
{
    __shared__ int lds[256];
    int tid = threadIdx.x;
    int base = blockIdx.x * SCAN_CHUNK + tid * 4;
    int c0 = 0, c1 = 0, c2 = 0, c3 = 0;
    if (base + 3 < n) {
        int4 v = *reinterpret_cast<const int4*>(counts + base);
        c0 = v.x; c1 = v.y; c2 = v.z; c3 = v.w;
    } else {
        if (base + 0 < n) c0 = counts[base + 0];
        if (base + 1 < n) c1 = counts[base + 1];
        if (base + 2 < n) c2 = counts[base + 2];
        if (base + 3 < n) c3 = counts[base + 3];
    }
    int s = c0 + c1 + c2 + c3;
    lds[tid] = s;
    __syncthreads();
    for (int off = 1; off < 256; off <<= 1) {
        int v = (tid >= off) ? lds[tid - off] : 0;
        __syncthreads();
        lds[tid] += v;
        __syncthreads();
    }
    int incl = lds[tid];
    int ex = incl - s;
    if (tid == 255) bsum[blockIdx.x] = incl;
    if (base + 0 < n) excl[base + 0] = ex;
    if (base + 1 < n) excl[base + 1] = ex + c0;
    if (base + 2 < n) excl[base + 2] = ex + c0 + c1;
    if (base + 3 < n) excl[base + 3] = ex + c0 + c1 + c2;
}

__global__ __launch_bounds__(64) void scan2_kernel(int* __restrict__ bsum, int nb)
{
    int lane = threadIdx.x;
    int v = (lane < nb) ? bsum[lane] : 0;
    int orig = v;
    for (int off = 1; off < 64; off <<= 1) {
        int t = __shfl_up(v, off);
        if (lane >= off) v += t;
    }
    if (lane < nb) bsum[lane] = v - orig;
}

__global__ __launch_bounds__(256) void scan3_kernel(
    const int* __restrict__ excl, const int* __restrict__ bsum,
    int* __restrict__ rp, int n, int n_edges)
{
    int i = blockIdx.x * 256 + threadIdx.x;
    if (i < n) rp[i] = excl[i] + bsum[i / SCAN_CHUNK];
    if (i == 0) rp[n] = n_edges;
}

__global__ __launch_bounds__(256) void fill2_kernel(
    const int* __restrict__ src, const int* __restrict__ dst,
    const int* __restrict__ rp, const int* __restrict__ loc,
    int* __restrict__ csr, int n_edges)
{
    int t = blockIdx.x * 256 + threadIdx.x;
    int e4 = t * 4;
    if (e4 + 4 <= n_edges) {
        int4 d = *reinterpret_cast<const int4*>(dst + e4);
        int4 s = *reinterpret_cast<const int4*>(src + e4);
        int4 l = *reinterpret_cast<const int4*>(loc + e4);
        csr[rp[d.x] + l.x] = s.x;
        csr[rp[d.y] + l.y] = s.y;
        csr[rp[d.z] + l.z] = s.z;
        csr[rp[d.w] + l.w] = s.w;
    } else {
        for (int e = e4; e < n_edges; ++e)
            csr[rp[dst[e]] + loc[e]] = src[e];
    }
}

// ------- pull (bf16): xout[v] = bf16( sum_{e:dst=v} xin[src[e]] ) ----------
// 2 nodes/wave; 16-lane groups x uint2 => one vmem instr covers 4 rows.
__global__ __launch_bounds__(256) void pull_bf16_kernel(
    const unsigned short* __restrict__ xin, unsigned short* __restrict__ xout,
    const int* __restrict__ rp, const int* __restrict__ csr, int n_nodes)
{
    int tid  = threadIdx.x;
    int wid  = (blockIdx.x * 256 + tid) >> 6;
    int lane = tid & 63;
    int half = lane >> 5;        // node within wave
    int hl   = lane & 31;        // lane within half
    int hb   = half << 5;        // half base
    int g    = (lane >> 4) & 1;  // edge-group within half
    int cl   = lane & 15;        // uint2 chunk within 128B row
    int node = wid * 2 + half;

    int beg = 0, end = 0;
    if (node < n_nodes) { beg = rp[node]; end = rp[node + 1]; }
    int cnt  = end - beg;
    int cntO = __shfl_xor(cnt, 32);
    int maxcnt = cnt > cntO ? cnt : cntO;   // wave-uniform

    const uint2* xu = reinterpret_cast<const uint2*>(xin);
    float a0 = 0.f, a1 = 0.f, a2 = 0.f, a3 = 0.f;

    for (int base = 0; base < maxcnt; base += 32) {
        int t = base + hl;
        int idx = (t < cnt) ? csr[beg + t] : 0;     // coalesced per half-wave
        #pragma unroll
        for (int ii = 0; ii < 8; ++ii) {            // edges 2*ii+g = 0..15
            int el = 2 * ii + g;
            int s = __shfl(idx, hb + el);
            if (base + el < cnt) {
                uint2 u = xu[(size_t)s * 16 + cl];
                a0 += bflo(u.x); a1 += bfhi(u.x);
                a2 += bflo(u.y); a3 += bfhi(u.y);
            }
        }
        if (maxcnt - base > 16) {
            #pragma unroll
            for (int ii = 8; ii < 16; ++ii) {       // edges 16..31
                int el = 2 * ii + g;
                int s = __shfl(idx, hb + el);
                if (base + el < cnt) {
                    uint2 u = xu[(size_t)s * 16 + cl];
                    a0 += bflo(u.x); a1 += bfhi(u.x);
                    a2 += bflo(u.y); a3 += bfhi(u.y);
                }
            }
        }
    }

    // combine the two edge-groups (xor 16 swaps g0<->g1 within each half)
    a0 += __shfl_xor(a0, 16); a1 += __shfl_xor(a1, 16);
    a2 += __shfl_xor(a2, 16); a3 += __shfl_xor(a3, 16);

    if (node < n_nodes && g == 0) {
        uint2 o;
        o.x = bf16r(a0) | (bf16r(a1) << 16);
        o.y = bf16r(a2) | (bf16r(a3) << 16);
        reinterpret_cast<uint2*>(xout)[(size_t)node * 16 + cl] = o;
    }
}

// ---------------- fallback (atomic push) if ws too small -------------------
__global__ __launch_bounds__(256) void scatter_kernel(
    const float* __restrict__ xin, float* __restrict__ xout,
    const int* __restrict__ src, const int* __restrict__ dst, int n_edges)
{
    int t = blockIdx.x * blockDim.x + threadIdx.x;
    int e = t >> 4;
    if (e >= n_edges) return;
    int c = (t & 15) * 4;
    int s = src[e];
    int d = dst[e];
    const float4 v = *reinterpret_cast<const float4*>(xin + (size_t)s * D + c);
    float* o = xout + (size_t)d * D + c;
    atomicAdd(o + 0, v.x);
    atomicAdd(o + 1, v.y);
    atomicAdd(o + 2, v.z);
    atomicAdd(o + 3, v.w);
}

extern "C" void kernel_launch(void* const* d_in, const int* in_sizes, int n_in,
                              void* d_out, int out_size, void* d_ws, size_t ws_size,
                              hipStream_t stream) {
    const float* x  = (const float*)d_in[0];
    const int*   ei = (const int*)d_in[1];
    const float* W  = (const float*)d_in[2];
    const float* b  = (const float*)d_in[3];
    float* y = (float*)d_out;

    int n_nodes = in_sizes[0] / D;   // 50000
    int n_edges = in_sizes[1] / 2;   // 800000
    const int* src = ei;
    const int* dst = ei + n_edges;

    int n_pad = ((n_nodes + SCAN_CHUNK - 1) / SCAN_CHUNK) * SCAN_CHUNK; // 50176
    int nblk  = n_pad / SCAN_CHUNK;                                      // 49

    size_t bufElems = (size_t)n_nodes * D;          // 3.2M
    unsigned short* xb = (unsigned short*)d_ws;     // bf16 x
    unsigned short* Ab = xb + bufElems;             // bf16 agg ping
    unsigned short* Bb = Ab + bufElems;             // bf16 agg pong
    int* counts = (int*)(Bb + bufElems);
    int* excl   = counts + n_pad;
    int* rp     = excl + n_pad;        // n_nodes+1 used
    int* bsum   = rp + n_pad;          // 64
    int* loc    = bsum + 64;           // n_edges
    int* csr    = loc + n_edges;       // n_edges

    size_t needed = (char*)(csr + n_edges) - (char*)d_ws;

    dim3 tb(256);
    dim3 tg((n_nodes + 3) / 4);
    int e4grid = (n_edges / 4 + 255) / 256;
    int ngrid  = (n_nodes + 255) / 256;
    int n8     = (int)(bufElems / 8);
    int cgrid  = (n8 + 255) / 256;
    int pgrid  = ((n_nodes + 1) / 2 + 3) / 4;   // 2 nodes/wave, 4 waves/block

    if (needed <= ws_size) {
        // ---- bf16 copy of x + CSR build ----
        cvt_kernel<<<cgrid, tb, 0, stream>>>(x, xb, n8);
        hipMemsetAsync(counts, 0, (size_t)n_pad * sizeof(int), stream);
        hist_loc_kernel<<<e4grid, tb, 0, stream>>>(dst, counts, loc, n_edges);
        scan1_kernel<<<nblk, tb, 0, stream>>>(counts, excl, bsum, n_nodes);
        scan2_kernel<<<1, 64, 0, stream>>>(bsum, nblk);
        scan3_kernel<<<ngrid, tb, 0, stream>>>(excl, bsum, rp, n_nodes, n_edges);
        fill2_kernel<<<e4grid, tb, 0, stream>>>(src, dst, rp, loc, csr, n_edges);

        // ---- tap 0 (f32) + pull/tap chain (bf16 data, f32 accumulate) ----
        tap_kernel<<<tg, tb, 0, stream>>>(x, W, b, y, n_nodes, 1);

        pull_bf16_kernel<<<pgrid, tb, 0, stream>>>(xb, Ab, rp, csr, n_nodes);
        tap_bf16_kernel<<<tg, tb, 0, stream>>>(Ab, W + 1 * D * D, b + 1 * D, y, n_nodes);

        pull_bf16_kernel<<<pgrid, tb, 0, stream>>>(Ab, Bb, rp, csr, n_nodes);
        tap_bf16_kernel<<<tg, tb, 0, stream>>>(Bb, W + 2 * D * D, b + 2 * D, y, n_nodes);

        pull_bf16_kernel<<<pgrid, tb, 0, stream>>>(Bb, Ab, rp, csr, n_nodes);
        tap_bf16_kernel<<<tg, tb, 0, stream>>>(Ab, W + 3 * D * D, b + 3 * D, y, n_nodes);
    } else {
        // ---- fallback: atomic push path (f32) ----
        float* A = (float*)d_ws;
        float* B = A + bufElems;
        size_t bufBytes = bufElems * sizeof(float);
        int sgrid = (n_edges * 16 + 255) / 256;
        hipMemsetAsync(A, 0, bufBytes, stream);
        hipMemsetAsync(B, 0, bufBytes, stream);
        tap_kernel<<<tg, tb, 0, stream>>>(x, W, b, y, n_nodes, 1);
        scatter_kernel<<<sgrid, tb, 0, stream>>>(x, A, src, dst, n_edges);
        tap_kernel<<<tg, tb, 0, stream>>>(A, W + D * D, b + D, y, n_nodes, 0);
        scatter_kernel<<<sgrid, tb, 0, stream>>>(A, B, src, dst, n_edges);
        hipMemsetAsync(A, 0, bufBytes, stream);
        tap_kernel<<<tg, tb, 0, stream>>>(B, W + 2 * D * D, b + 2 * D, y, n_nodes, 0);
        scatter_kernel<<<sgrid, tb, 0, stream>>>(B, A, src, dst, n_edges);
        tap_kernel<<<tg, tb, 0, stream>>>(A, W + 3 * D * D, b + 3 * D, y, n_nodes, 0);
    }
}

// Round 8
// 250.314 us; speedup vs baseline: 1.0052x; 1.0052x over previous
//
#include <hip/hip_runtime.h>

#define D 64
#define SCAN_CHUNK 1024   // elements per scan1 block (256 thr x 4)

__device__ __forceinline__ unsigned int bf16r(float f) {
    unsigned int u = __float_as_uint(f);
    return (u + 0x7fffu + ((u >> 16) & 1u)) >> 16;   // RNE to bf16
}
__device__ __forceinline__ float bflo(unsigned int u) { return __uint_as_float(u << 16); }
__device__ __forceinline__ float bfhi(unsigned int u) { return __uint_as_float(u & 0xffff0000u); }

// ---------------- f32 -> bf16 row conversion (8 elems/thread) --------------
__global__ __launch_bounds__(256) void cvt_kernel(
    const float* __restrict__ in, unsigned short* __restrict__ out, int n8)
{
    int t = blockIdx.x * 256 + threadIdx.x;
    if (t >= n8) return;
    const float4* p = reinterpret_cast<const float4*>(in) + (size_t)t * 2;
    float4 v0 = p[0], v1 = p[1];
    uint4 o;
    o.x = bf16r(v0.x) | (bf16r(v0.y) << 16);
    o.y = bf16r(v0.z) | (bf16r(v0.w) << 16);
    o.z = bf16r(v1.x) | (bf16r(v1.y) << 16);
    o.w = bf16r(v1.z) | (bf16r(v1.w) << 16);
    reinterpret_cast<uint4*>(out)[t] = o;
}

// ---------------- tap0 (f32 in): y[row][j] = sum_i x[row][i]*W[j][i]+b[j] --
__global__ __launch_bounds__(256) void tap_kernel(
    const float* __restrict__ xin, const float* __restrict__ W,
    const float* __restrict__ b, float* __restrict__ y,
    int n_nodes, int first)
{
    __shared__ float Wt[D * (D + 1)];
    __shared__ float bs[D];
    __shared__ float xs[4][D];

    int tid = threadIdx.x;
    for (int t = tid; t < D * D; t += 256) {
        int j = t >> 6, i = t & 63;
        Wt[i * (D + 1) + j] = W[t];
    }
    if (tid < D) bs[tid] = b[tid];

    int rl = tid >> 6;
    int j  = tid & 63;
    int row = blockIdx.x * 4 + rl;
    if (row < n_nodes) xs[rl][j] = xin[(size_t)row * D + j];
    __syncthreads();

    if (row >= n_nodes) return;

    float acc = bs[j];
    #pragma unroll 8
    for (int i = 0; i < D; ++i)
        acc = fmaf(xs[rl][i], Wt[i * (D + 1) + j], acc);

    float* yp = y + (size_t)row * D + j;
    *yp = first ? acc : (*yp + acc);
}

// ---------------- tap (bf16 in): y[row][j] += sum_i xb[row][i]*W[j][i]+b[j]
__global__ __launch_bounds__(256) void tap_bf16_kernel(
    const unsigned short* __restrict__ xin, const float* __restrict__ W,
    const float* __restrict__ b, float* __restrict__ y, int n_nodes)
{
    __shared__ float Wt[D * (D + 1)];
    __shared__ float bs[D];
    __shared__ float xs[4][D];

    int tid = threadIdx.x;
    for (int t = tid; t < D * D; t += 256) {
        int j = t >> 6, i = t & 63;
        Wt[i * (D + 1) + j] = W[t];
    }
    if (tid < D) bs[tid] = b[tid];

    int rl = tid >> 6;
    int lane = tid & 63;
    int row = blockIdx.x * 4 + rl;
    if (row < n_nodes && lane < 32) {
        unsigned int u = reinterpret_cast<const unsigned int*>(xin + (size_t)row * D)[lane];
        xs[rl][2 * lane]     = bflo(u);
        xs[rl][2 * lane + 1] = bfhi(u);
    }
    __syncthreads();

    if (row >= n_nodes) return;

    float acc = bs[lane];
    #pragma unroll 8
    for (int i = 0; i < D; ++i)
        acc = fmaf(xs[rl][i], Wt[i * (D + 1) + lane], acc);

    y[(size_t)row * D + lane] += acc;
}

// ---------------- CSR build ------------------------------------------------
__global__ __launch_bounds__(256) void hist_loc_kernel(
    const int* __restrict__ dst, int* __restrict__ counts,
    int* __restrict__ loc, int n_edges)
{
    int t = blockIdx.x * 256 + threadIdx.x;
    int e4 = t * 4;
    if (e4 + 4 <= n_edges) {
        int4 d = *reinterpret_cast<const int4*>(dst + e4);
        int4 l;
        l.x = atomicAdd(&counts[d.x], 1);
        l.y = atomicAdd(&counts[d.y], 1);
        l.z = atomicAdd(&counts[d.z], 1);
        l.w = atomicAdd(&counts[d.w], 1);
        *reinterpret_cast<int4*>(loc + e4) = l;
    } else {
        for (int e = e4; e < n_edges; ++e)
            loc[e] = atomicAdd(&counts[dst[e]], 1);
    }
}

__global__ __launch_bounds__(256) void scan1_kernel(
    const int* __restrict__ counts, int* __restrict__ excl,
    int* __restrict__ bsum, int n)
{
    __shared__ int lds[256];
    int tid = threadIdx.x;
    int base = blockIdx.x * SCAN_CHUNK + tid * 4;
    int c0 = 0, c1 = 0, c2 = 0, c3 = 0;
    if (base + 3 < n) {
        int4 v = *reinterpret_cast<const int4*>(counts + base);
        c0 = v.x; c1 = v.y; c2 = v.z; c3 = v.w;
    } else {
        if (base + 0 < n) c0 = counts[base + 0];
        if (base + 1 < n) c1 = counts[base + 1];
        if (base + 2 < n) c2 = counts[base + 2];
        if (base + 3 < n) c3 = counts[base + 3];
    }
    int s = c0 + c1 + c2 + c3;
    lds[tid] = s;
    __syncthreads();
    for (int off = 1; off < 256; off <<= 1) {
        int v = (tid >= off) ? lds[tid - off] : 0;
        __syncthreads();
        lds[tid] += v;
        __syncthreads();
    }
    int incl = lds[tid];
    int ex = incl - s;
    if (tid == 255) bsum[blockIdx.x] = incl;
    if (base + 0 < n) excl[base + 0] = ex;
    if (base + 1 < n) excl[base + 1] = ex + c0;
    if (base + 2 < n) excl[base + 2] = ex + c0 + c1;
    if (base + 3 < n) excl[base + 3] = ex + c0 + c1 + c2;
}

__global__ __launch_bounds__(64) void scan2_kernel(int* __restrict__ bsum, int nb)
{
    int lane = threadIdx.x;
    int v = (lane < nb) ? bsum[lane] : 0;
    int orig = v;
    for (int off = 1; off < 64; off <<= 1) {
        int t = __shfl_up(v, off);
        if (lane >= off) v += t;
    }
    if (lane < nb) bsum[lane] = v - orig;
}

__global__ __launch_bounds__(256) void scan3_kernel(
    const int* __restrict__ excl, const int* __restrict__ bsum,
    int* __restrict__ rp, int n, int n_edges)
{
    int i = blockIdx.x * 256 + threadIdx.x;
    if (i < n) rp[i] = excl[i] + bsum[i / SCAN_CHUNK];
    if (i == 0) rp[n] = n_edges;
}

__global__ __launch_bounds__(256) void fill2_kernel(
    const int* __restrict__ src, const int* __restrict__ dst,
    const int* __restrict__ rp, const int* __restrict__ loc,
    int* __restrict__ csr, int n_edges)
{
    int t = blockIdx.x * 256 + threadIdx.x;
    int e4 = t * 4;
    if (e4 + 4 <= n_edges) {
        int4 d = *reinterpret_cast<const int4*>(dst + e4);
        int4 s = *reinterpret_cast<const int4*>(src + e4);
        int4 l = *reinterpret_cast<const int4*>(loc + e4);
        csr[rp[d.x] + l.x] = s.x;
        csr[rp[d.y] + l.y] = s.y;
        csr[rp[d.z] + l.z] = s.z;
        csr[rp[d.w] + l.w] = s.w;
    } else {
        for (int e = e4; e < n_edges; ++e)
            csr[rp[dst[e]] + loc[e]] = src[e];
    }
}

// ------- pull (bf16): xout[v] = bf16( sum_{e:dst=v} xin[src[e]] ) ----------
// 2 nodes/wave; 16-lane groups x uint2 => one vmem instr covers 4 rows.
__global__ __launch_bounds__(256) void pull_bf16_kernel(
    const unsigned short* __restrict__ xin, unsigned short* __restrict__ xout,
    const int* __restrict__ rp, const int* __restrict__ csr, int n_nodes)
{
    int tid  = threadIdx.x;
    int wid  = (blockIdx.x * 256 + tid) >> 6;
    int lane = tid & 63;
    int half = lane >> 5;        // node within wave
    int hl   = lane & 31;        // lane within half
    int hb   = half << 5;        // half base
    int g    = (lane >> 4) & 1;  // edge-group within half
    int cl   = lane & 15;        // uint2 chunk within 128B row
    int node = wid * 2 + half;

    int beg = 0, end = 0;
    if (node < n_nodes) { beg = rp[node]; end = rp[node + 1]; }
    int cnt  = end - beg;
    int cntO = __shfl_xor(cnt, 32);
    int maxcnt = cnt > cntO ? cnt : cntO;   // wave-uniform

    const uint2* xu = reinterpret_cast<const uint2*>(xin);
    float a0 = 0.f, a1 = 0.f, a2 = 0.f, a3 = 0.f;

    for (int base = 0; base < maxcnt; base += 32) {
        int t = base + hl;
        int idx = (t < cnt) ? csr[beg + t] : 0;     // coalesced per half-wave
        #pragma unroll
        for (int ii = 0; ii < 8; ++ii) {            // edges 2*ii+g = 0..15
            int el = 2 * ii + g;
            int s = __shfl(idx, hb + el);
            if (base + el < cnt) {
                uint2 u = xu[(size_t)s * 16 + cl];
                a0 += bflo(u.x); a1 += bfhi(u.x);
                a2 += bflo(u.y); a3 += bfhi(u.y);
            }
        }
        if (maxcnt - base > 16) {
            #pragma unroll
            for (int ii = 8; ii < 16; ++ii) {       // edges 16..31
                int el = 2 * ii + g;
                int s = __shfl(idx, hb + el);
                if (base + el < cnt) {
                    uint2 u = xu[(size_t)s * 16 + cl];
                    a0 += bflo(u.x); a1 += bfhi(u.x);
                    a2 += bflo(u.y); a3 += bfhi(u.y);
                }
            }
        }
    }

    // combine the two edge-groups (xor 16 swaps g0<->g1 within each half)
    a0 += __shfl_xor(a0, 16); a1 += __shfl_xor(a1, 16);
    a2 += __shfl_xor(a2, 16); a3 += __shfl_xor(a3, 16);

    if (node < n_nodes && g == 0) {
        uint2 o;
        o.x = bf16r(a0) | (bf16r(a1) << 16);
        o.y = bf16r(a2) | (bf16r(a3) << 16);
        reinterpret_cast<uint2*>(xout)[(size_t)node * 16 + cl] = o;
    }
}

// ---------------- fallback (atomic push) if ws too small -------------------
__global__ __launch_bounds__(256) void scatter_kernel(
    const float* __restrict__ xin, float* __restrict__ xout,
    const int* __restrict__ src, const int* __restrict__ dst, int n_edges)
{
    int t = blockIdx.x * blockDim.x + threadIdx.x;
    int e = t >> 4;
    if (e >= n_edges) return;
    int c = (t & 15) * 4;
    int s = src[e];
    int d = dst[e];
    const float4 v = *reinterpret_cast<const float4*>(xin + (size_t)s * D + c);
    float* o = xout + (size_t)d * D + c;
    atomicAdd(o + 0, v.x);
    atomicAdd(o + 1, v.y);
    atomicAdd(o + 2, v.z);
    atomicAdd(o + 3, v.w);
}

extern "C" void kernel_launch(void* const* d_in, const int* in_sizes, int n_in,
                              void* d_out, int out_size, void* d_ws, size_t ws_size,
                              hipStream_t stream) {
    const float* x  = (const float*)d_in[0];
    const int*   ei = (const int*)d_in[1];
    const float* W  = (const float*)d_in[2];
    const float* b  = (const float*)d_in[3];
    float* y = (float*)d_out;

    int n_nodes = in_sizes[0] / D;   // 50000
    int n_edges = in_sizes[1] / 2;   // 800000
    const int* src = ei;
    const int* dst = ei + n_edges;

    int n_pad = ((n_nodes + SCAN_CHUNK - 1) / SCAN_CHUNK) * SCAN_CHUNK; // 50176
    int nblk  = n_pad / SCAN_CHUNK;                                      // 49

    size_t bufElems = (size_t)n_nodes * D;          // 3.2M
    unsigned short* xb = (unsigned short*)d_ws;     // bf16 x
    unsigned short* Ab = xb + bufElems;             // bf16 agg1
    unsigned short* Bb = Ab + bufElems;             // bf16 agg2
    unsigned short* Cb = Bb + bufElems;             // bf16 agg3
    int* counts = (int*)(Cb + bufElems);
    int* excl   = counts + n_pad;
    int* rp     = excl + n_pad;        // n_nodes+1 used
    int* bsum   = rp + n_pad;          // 64
    int* loc    = bsum + 64;           // n_edges
    int* csr    = loc + n_edges;       // n_edges

    size_t needed = (char*)(csr + n_edges) - (char*)d_ws;

    dim3 tb(256);
    dim3 tg((n_nodes + 3) / 4);
    int e4grid = (n_edges / 4 + 255) / 256;
    int ngrid  = (n_nodes + 255) / 256;
    int n8     = (int)(bufElems / 8);
    int cgrid  = (n8 + 255) / 256;
    int pgrid  = ((n_nodes + 1) / 2 + 3) / 4;   // 2 nodes/wave, 4 waves/block

    if (needed <= ws_size) {
        // ---- bf16 copy of x + CSR build ----
        cvt_kernel<<<cgrid, tb, 0, stream>>>(x, xb, n8);
        hipMemsetAsync(counts, 0, (size_t)n_pad * sizeof(int), stream);
        hist_loc_kernel<<<e4grid, tb, 0, stream>>>(dst, counts, loc, n_edges);
        scan1_kernel<<<nblk, tb, 0, stream>>>(counts, excl, bsum, n_nodes);
        scan2_kernel<<<1, 64, 0, stream>>>(bsum, nblk);
        scan3_kernel<<<ngrid, tb, 0, stream>>>(excl, bsum, rp, n_nodes, n_edges);
        fill2_kernel<<<e4grid, tb, 0, stream>>>(src, dst, rp, loc, csr, n_edges);

        // ---- shift chain back-to-back (L2-hot producer->consumer) ----
        pull_bf16_kernel<<<pgrid, tb, 0, stream>>>(xb, Ab, rp, csr, n_nodes);
        pull_bf16_kernel<<<pgrid, tb, 0, stream>>>(Ab, Bb, rp, csr, n_nodes);
        pull_bf16_kernel<<<pgrid, tb, 0, stream>>>(Bb, Cb, rp, csr, n_nodes);

        // ---- tap phase (full-occupancy light kernels) ----
        tap_kernel<<<tg, tb, 0, stream>>>(x, W, b, y, n_nodes, 1);
        tap_bf16_kernel<<<tg, tb, 0, stream>>>(Ab, W + 1 * D * D, b + 1 * D, y, n_nodes);
        tap_bf16_kernel<<<tg, tb, 0, stream>>>(Bb, W + 2 * D * D, b + 2 * D, y, n_nodes);
        tap_bf16_kernel<<<tg, tb, 0, stream>>>(Cb, W + 3 * D * D, b + 3 * D, y, n_nodes);
    } else {
        // ---- fallback: atomic push path (f32) ----
        float* A = (float*)d_ws;
        float* B = A + bufElems;
        size_t bufBytes = bufElems * sizeof(float);
        int sgrid = (n_edges * 16 + 255) / 256;
        hipMemsetAsync(A, 0, bufBytes, stream);
        hipMemsetAsync(B, 0, bufBytes, stream);
        tap_kernel<<<tg, tb, 0, stream>>>(x, W, b, y, n_nodes, 1);
        scatter_kernel<<<sgrid, tb, 0, stream>>>(x, A, src, dst, n_edges);
        tap_kernel<<<tg, tb, 0, stream>>>(A, W + D * D, b + D, y, n_nodes, 0);
        scatter_kernel<<<sgrid, tb, 0, stream>>>(A, B, src, dst, n_edges);
        hipMemsetAsync(A, 0, bufBytes, stream);
        tap_kernel<<<tg, tb, 0, stream>>>(B, W + 2 * D * D, b + 2 * D, y, n_nodes, 0);
        scatter_kernel<<<sgrid, tb, 0, stream>>>(B, A, src, dst, n_edges);
        tap_kernel<<<tg, tb, 0, stream>>>(A, W + 3 * D * D, b + 3 * D, y, n_nodes, 0);
    }
}

// Round 9
// 220.056 us; speedup vs baseline: 1.1434x; 1.1375x over previous
//
#include <hip/hip_runtime.h>

#define D 64
#define SCAN_CHUNK 1024   // elements per scan1 block (256 thr x 4)

__device__ __forceinline__ unsigned int bf16r(float f) {
    unsigned int u = __float_as_uint(f);
    return (u + 0x7fffu + ((u >> 16) & 1u)) >> 16;   // RNE to bf16
}
__device__ __forceinline__ float bflo(unsigned int u) { return __uint_as_float(u << 16); }
__device__ __forceinline__ float bfhi(unsigned int u) { return __uint_as_float(u & 0xffff0000u); }

// ---- fused prep: blocks [0,cgrid) cvt x->bf16 ; blocks [cgrid,..) hist ----
__global__ __launch_bounds__(256) void prep_kernel(
    const float* __restrict__ x, unsigned short* __restrict__ xb, int n8,
    const int* __restrict__ dst, int* __restrict__ counts,
    int* __restrict__ loc, int n_edges, int cgrid)
{
    int tid = threadIdx.x;
    if ((int)blockIdx.x < cgrid) {
        int t = blockIdx.x * 256 + tid;
        if (t >= n8) return;
        const float4* p = reinterpret_cast<const float4*>(x) + (size_t)t * 2;
        float4 v0 = p[0], v1 = p[1];
        uint4 o;
        o.x = bf16r(v0.x) | (bf16r(v0.y) << 16);
        o.y = bf16r(v0.z) | (bf16r(v0.w) << 16);
        o.z = bf16r(v1.x) | (bf16r(v1.y) << 16);
        o.w = bf16r(v1.z) | (bf16r(v1.w) << 16);
        reinterpret_cast<uint4*>(xb)[t] = o;
    } else {
        int t = (blockIdx.x - cgrid) * 256 + tid;
        int e4 = t * 4;
        if (e4 + 4 <= n_edges) {
            int4 d = *reinterpret_cast<const int4*>(dst + e4);
            int4 l;
            l.x = atomicAdd(&counts[d.x], 1);
            l.y = atomicAdd(&counts[d.y], 1);
            l.z = atomicAdd(&counts[d.z], 1);
            l.w = atomicAdd(&counts[d.w], 1);
            *reinterpret_cast<int4*>(loc + e4) = l;
        } else {
            for (int e = e4; e < n_edges; ++e)
                loc[e] = atomicAdd(&counts[dst[e]], 1);
        }
    }
}

// ---------------- fallback tap (f32 in) ------------------------------------
__global__ __launch_bounds__(256) void tap_kernel(
    const float* __restrict__ xin, const float* __restrict__ W,
    const float* __restrict__ b, float* __restrict__ y,
    int n_nodes, int first)
{
    __shared__ float Wt[D * (D + 1)];
    __shared__ float bs[D];
    __shared__ float xs[4][D];

    int tid = threadIdx.x;
    for (int t = tid; t < D * D; t += 256) {
        int j = t >> 6, i = t & 63;
        Wt[i * (D + 1) + j] = W[t];
    }
    if (tid < D) bs[tid] = b[tid];

    int rl = tid >> 6;
    int j  = tid & 63;
    int row = blockIdx.x * 4 + rl;
    if (row < n_nodes) xs[rl][j] = xin[(size_t)row * D + j];
    __syncthreads();

    if (row >= n_nodes) return;

    float acc = bs[j];
    #pragma unroll 8
    for (int i = 0; i < D; ++i)
        acc = fmaf(xs[rl][i], Wt[i * (D + 1) + j], acc);

    float* yp = y + (size_t)row * D + j;
    *yp = first ? acc : (*yp + acc);
}

// ------- tap01: y[row] = x@W0^T + A1@W1^T + (b0+b1)  (write) ---------------
__global__ __launch_bounds__(256) void tap01_kernel(
    const float* __restrict__ x, const unsigned short* __restrict__ A1,
    const float* __restrict__ W, const float* __restrict__ b,
    float* __restrict__ y, int n_nodes)
{
    __shared__ float Wt0[D * (D + 1)];
    __shared__ float Wt1[D * (D + 1)];
    __shared__ float bs[D];
    __shared__ float2 xs[4][D];

    int tid = threadIdx.x;
    for (int t = tid; t < D * D; t += 256) {
        int j = t >> 6, i = t & 63;
        Wt0[i * (D + 1) + j] = W[t];
        Wt1[i * (D + 1) + j] = W[D * D + t];
    }
    if (tid < D) bs[tid] = b[tid] + b[D + tid];
    __syncthreads();

    int w    = tid >> 6;
    int lane = tid & 63;
    int stride = gridDim.x * 4;

    for (int r0 = blockIdx.x * 4; r0 < n_nodes; r0 += stride) {
        int row = r0 + w;
        if (row < n_nodes) {
            size_t o = (size_t)row * D + lane;
            float xv = x[o];
            float a1 = __uint_as_float(((unsigned int)A1[o]) << 16);
            xs[w][lane] = make_float2(xv, a1);          // wave-private slot

            float acc = bs[lane];
            #pragma unroll 16
            for (int i = 0; i < D; ++i) {
                float2 v = xs[w][i];                    // same-addr broadcast
                acc = fmaf(v.x, Wt0[i * (D + 1) + lane],
                      fmaf(v.y, Wt1[i * (D + 1) + lane], acc));
            }
            y[o] = acc;
        }
    }
}

// ------- tap23: y[row] += A2@W2^T + A3@W3^T + (b2+b3)  (RMW) ---------------
__global__ __launch_bounds__(256) void tap23_kernel(
    const unsigned short* __restrict__ A2, const unsigned short* __restrict__ A3,
    const float* __restrict__ W, const float* __restrict__ b,
    float* __restrict__ y, int n_nodes)
{
    __shared__ float Wt2[D * (D + 1)];
    __shared__ float Wt3[D * (D + 1)];
    __shared__ float bs[D];
    __shared__ float2 xs[4][D];

    int tid = threadIdx.x;
    for (int t = tid; t < D * D; t += 256) {
        int j = t >> 6, i = t & 63;
        Wt2[i * (D + 1) + j] = W[2 * D * D + t];
        Wt3[i * (D + 1) + j] = W[3 * D * D + t];
    }
    if (tid < D) bs[tid] = b[2 * D + tid] + b[3 * D + tid];
    __syncthreads();

    int w    = tid >> 6;
    int lane = tid & 63;
    int stride = gridDim.x * 4;

    for (int r0 = blockIdx.x * 4; r0 < n_nodes; r0 += stride) {
        int row = r0 + w;
        if (row < n_nodes) {
            size_t o = (size_t)row * D + lane;
            float a2 = __uint_as_float(((unsigned int)A2[o]) << 16);
            float a3 = __uint_as_float(((unsigned int)A3[o]) << 16);
            xs[w][lane] = make_float2(a2, a3);

            float acc = bs[lane];
            #pragma unroll 16
            for (int i = 0; i < D; ++i) {
                float2 v = xs[w][i];
                acc = fmaf(v.x, Wt2[i * (D + 1) + lane],
                      fmaf(v.y, Wt3[i * (D + 1) + lane], acc));
            }
            y[o] += acc;
        }
    }
}

// ---------------- CSR scan -------------------------------------------------
__global__ __launch_bounds__(256) void scan1_kernel(
    const int* __restrict__ counts, int* __restrict__ excl,
    int* __restrict__ bsum, int n)
{
    __shared__ int lds[256];
    int tid = threadIdx.x;
    int base = blockIdx.x * SCAN_CHUNK + tid * 4;
    int c0 = 0, c1 = 0, c2 = 0, c3 = 0;
    if (base + 3 < n) {
        int4 v = *reinterpret_cast<const int4*>(counts + base);
        c0 = v.x; c1 = v.y; c2 = v.z; c3 = v.w;
    } else {
        if (base + 0 < n) c0 = counts[base + 0];
        if (base + 1 < n) c1 = counts[base + 1];
        if (base + 2 < n) c2 = counts[base + 2];
        if (base + 3 < n) c3 = counts[base + 3];
    }
    int s = c0 + c1 + c2 + c3;
    lds[tid] = s;
    __syncthreads();
    for (int off = 1; off < 256; off <<= 1) {
        int v = (tid >= off) ? lds[tid - off] : 0;
        __syncthreads();
        lds[tid] += v;
        __syncthreads();
    }
    int incl = lds[tid];
    int ex = incl - s;
    if (tid == 255) bsum[blockIdx.x] = incl;
    if (base + 0 < n) excl[base + 0] = ex;
    if (base + 1 < n) excl[base + 1] = ex + c0;
    if (base + 2 < n) excl[base + 2] = ex + c0 + c1;
    if (base + 3 < n) excl[base + 3] = ex + c0 + c1 + c2;
}

// scan3 with in-kernel (redundant per-block) scan of the <=64 block sums
__global__ __launch_bounds__(256) void scan3b_kernel(
    const int* __restrict__ excl, const int* __restrict__ bsum,
    int* __restrict__ rp, int n, int n_edges, int nblk)
{
    __shared__ int sb[64];
    int tid = threadIdx.x;
    if (tid < 64) {
        int v = (tid < nblk) ? bsum[tid] : 0;
        int orig = v;
        for (int off = 1; off < 64; off <<= 1) {
            int t = __shfl_up(v, off);
            if (tid >= off) v += t;
        }
        sb[tid] = v - orig;    // exclusive prefix of block sums
    }
    __syncthreads();
    int i = blockIdx.x * 256 + tid;
    if (i < n) rp[i] = excl[i] + sb[i / SCAN_CHUNK];
    if (i == 0) rp[n] = n_edges;
}

__global__ __launch_bounds__(256) void fill2_kernel(
    const int* __restrict__ src, const int* __restrict__ dst,
    const int* __restrict__ rp, const int* __restrict__ loc,
    int* __restrict__ csr, int n_edges)
{
    int t = blockIdx.x * 256 + threadIdx.x;
    int e4 = t * 4;
    if (e4 + 4 <= n_edges) {
        int4 d = *reinterpret_cast<const int4*>(dst + e4);
        int4 s = *reinterpret_cast<const int4*>(src + e4);
        int4 l = *reinterpret_cast<const int4*>(loc + e4);
        csr[rp[d.x] + l.x] = s.x;
        csr[rp[d.y] + l.y] = s.y;
        csr[rp[d.z] + l.z] = s.z;
        csr[rp[d.w] + l.w] = s.w;
    } else {
        for (int e = e4; e < n_edges; ++e)
            csr[rp[dst[e]] + loc[e]] = src[e];
    }
}

// ------- pull (bf16): xout[v] = bf16( sum_{e:dst=v} xin[src[e]] ) ----------
// 2 nodes/wave; 16-lane groups x uint2 => one vmem instr covers 4 rows.
__global__ __launch_bounds__(256) void pull_bf16_kernel(
    const unsigned short* __restrict__ xin, unsigned short* __restrict__ xout,
    const int* __restrict__ rp, const int* __restrict__ csr, int n_nodes)
{
    int tid  = threadIdx.x;
    int wid  = (blockIdx.x * 256 + tid) >> 6;
    int lane = tid & 63;
    int half = lane >> 5;        // node within wave
    int hl   = lane & 31;        // lane within half
    int hb   = half << 5;        // half base
    int g    = (lane >> 4) & 1;  // edge-group within half
    int cl   = lane & 15;        // uint2 chunk within 128B row
    int node = wid * 2 + half;

    int beg = 0, end = 0;
    if (node < n_nodes) { beg = rp[node]; end = rp[node + 1]; }
    int cnt  = end - beg;
    int cntO = __shfl_xor(cnt, 32);
    int maxcnt = cnt > cntO ? cnt : cntO;   // wave-uniform

    const uint2* xu = reinterpret_cast<const uint2*>(xin);
    float a0 = 0.f, a1 = 0.f, a2 = 0.f, a3 = 0.f;

    for (int base = 0; base < maxcnt; base += 32) {
        int t = base + hl;
        int idx = (t < cnt) ? csr[beg + t] : 0;     // coalesced per half-wave
        #pragma unroll
        for (int ii = 0; ii < 8; ++ii) {            // edges 2*ii+g = 0..15
            int el = 2 * ii + g;
            int s = __shfl(idx, hb + el);
            if (base + el < cnt) {
                uint2 u = xu[(size_t)s * 16 + cl];
                a0 += bflo(u.x); a1 += bfhi(u.x);
                a2 += bflo(u.y); a3 += bfhi(u.y);
            }
        }
        if (maxcnt - base > 16) {
            #pragma unroll
            for (int ii = 8; ii < 16; ++ii) {       // edges 16..31
                int el = 2 * ii + g;
                int s = __shfl(idx, hb + el);
                if (base + el < cnt) {
                    uint2 u = xu[(size_t)s * 16 + cl];
                    a0 += bflo(u.x); a1 += bfhi(u.x);
                    a2 += bflo(u.y); a3 += bfhi(u.y);
                }
            }
        }
    }

    // combine the two edge-groups (xor 16 swaps g0<->g1 within each half)
    a0 += __shfl_xor(a0, 16); a1 += __shfl_xor(a1, 16);
    a2 += __shfl_xor(a2, 16); a3 += __shfl_xor(a3, 16);

    if (node < n_nodes && g == 0) {
        uint2 o;
        o.x = bf16r(a0) | (bf16r(a1) << 16);
        o.y = bf16r(a2) | (bf16r(a3) << 16);
        reinterpret_cast<uint2*>(xout)[(size_t)node * 16 + cl] = o;
    }
}

// ---------------- fallback (atomic push) if ws too small -------------------
__global__ __launch_bounds__(256) void scatter_kernel(
    const float* __restrict__ xin, float* __restrict__ xout,
    const int* __restrict__ src, const int* __restrict__ dst, int n_edges)
{
    int t = blockIdx.x * blockDim.x + threadIdx.x;
    int e = t >> 4;
    if (e >= n_edges) return;
    int c = (t & 15) * 4;
    int s = src[e];
    int d = dst[e];
    const float4 v = *reinterpret_cast<const float4*>(xin + (size_t)s * D + c);
    float* o = xout + (size_t)d * D + c;
    atomicAdd(o + 0, v.x);
    atomicAdd(o + 1, v.y);
    atomicAdd(o + 2, v.z);
    atomicAdd(o + 3, v.w);
}

extern "C" void kernel_launch(void* const* d_in, const int* in_sizes, int n_in,
                              void* d_out, int out_size, void* d_ws, size_t ws_size,
                              hipStream_t stream) {
    const float* x  = (const float*)d_in[0];
    const int*   ei = (const int*)d_in[1];
    const float* W  = (const float*)d_in[2];
    const float* b  = (const float*)d_in[3];
    float* y = (float*)d_out;

    int n_nodes = in_sizes[0] / D;   // 50000
    int n_edges = in_sizes[1] / 2;   // 800000
    const int* src = ei;
    const int* dst = ei + n_edges;

    int n_pad = ((n_nodes + SCAN_CHUNK - 1) / SCAN_CHUNK) * SCAN_CHUNK; // 50176
    int nblk  = n_pad / SCAN_CHUNK;                                      // 49

    size_t bufElems = (size_t)n_nodes * D;          // 3.2M
    unsigned short* xb = (unsigned short*)d_ws;     // bf16 x
    unsigned short* Ab = xb + bufElems;             // bf16 agg1
    unsigned short* Bb = Ab + bufElems;             // bf16 agg2
    unsigned short* Cb = Bb + bufElems;             // bf16 agg3
    int* counts = (int*)(Cb + bufElems);
    int* excl   = counts + n_pad;
    int* rp     = excl + n_pad;        // n_nodes+1 used
    int* bsum   = rp + n_pad;          // 64
    int* loc    = bsum + 64;           // n_edges
    int* csr    = loc + n_edges;       // n_edges

    size_t needed = (char*)(csr + n_edges) - (char*)d_ws;

    dim3 tb(256);
    dim3 tg((n_nodes + 3) / 4);
    int e4grid = (n_edges / 4 + 255) / 256;
    int ngrid  = (n_nodes + 255) / 256;
    int n8     = (int)(bufElems / 8);
    int cgrid  = (n8 + 255) / 256;
    int pgrid  = ((n_nodes + 1) / 2 + 3) / 4;   // 2 nodes/wave, 4 waves/block

    if (needed <= ws_size) {
        // ---- prep: memset counts, fused cvt+hist, scan, fill ----
        hipMemsetAsync(counts, 0, (size_t)n_pad * sizeof(int), stream);
        prep_kernel<<<cgrid + e4grid, tb, 0, stream>>>(x, xb, n8, dst, counts,
                                                       loc, n_edges, cgrid);
        scan1_kernel<<<nblk, tb, 0, stream>>>(counts, excl, bsum, n_nodes);
        scan3b_kernel<<<ngrid, tb, 0, stream>>>(excl, bsum, rp, n_nodes,
                                                n_edges, nblk);
        fill2_kernel<<<e4grid, tb, 0, stream>>>(src, dst, rp, loc, csr, n_edges);

        // ---- shift chain back-to-back (L2-hot producer->consumer) ----
        pull_bf16_kernel<<<pgrid, tb, 0, stream>>>(xb, Ab, rp, csr, n_nodes);
        pull_bf16_kernel<<<pgrid, tb, 0, stream>>>(Ab, Bb, rp, csr, n_nodes);
        pull_bf16_kernel<<<pgrid, tb, 0, stream>>>(Bb, Cb, rp, csr, n_nodes);

        // ---- tap phase: two 2-tap fused kernels (33KB LDS -> 4 blk/CU) ----
        tap01_kernel<<<1024, tb, 0, stream>>>(x, Ab, W, b, y, n_nodes);
        tap23_kernel<<<1024, tb, 0, stream>>>(Bb, Cb, W, b, y, n_nodes);
    } else {
        // ---- fallback: atomic push path (f32) ----
        float* A = (float*)d_ws;
        float* B = A + bufElems;
        size_t bufBytes = bufElems * sizeof(float);
        int sgrid = (n_edges * 16 + 255) / 256;
        hipMemsetAsync(A, 0, bufBytes, stream);
        hipMemsetAsync(B, 0, bufBytes, stream);
        tap_kernel<<<tg, tb, 0, stream>>>(x, W, b, y, n_nodes, 1);
        scatter_kernel<<<sgrid, tb, 0, stream>>>(x, A, src, dst, n_edges);
        tap_kernel<<<tg, tb, 0, stream>>>(A, W + D * D, b + D, y, n_nodes, 0);
        scatter_kernel<<<sgrid, tb, 0, stream>>>(A, B, src, dst, n_edges);
        hipMemsetAsync(A, 0, bufBytes, stream);
        tap_kernel<<<tg, tb, 0, stream>>>(B, W + 2 * D * D, b + 2 * D, y, n_nodes, 0);
        scatter_kernel<<<sgrid, tb, 0, stream>>>(B, A, src, dst, n_edges);
        tap_kernel<<<tg, tb, 0, stream>>>(A, W + 3 * D * D, b + 3 * D, y, n_nodes, 0);
    }
}

// Round 10
// 218.351 us; speedup vs baseline: 1.1523x; 1.0078x over previous
//
#include <hip/hip_runtime.h>

#define D 64
#define SCAN_CHUNK 1024   // elements per scan1 block (256 thr x 4)
#define NSEG 16           // histogram replicas (contention divider)

__device__ __forceinline__ unsigned int bf16r(float f) {
    unsigned int u = __float_as_uint(f);
    return (u + 0x7fffu + ((u >> 16) & 1u)) >> 16;   // RNE to bf16
}
__device__ __forceinline__ float bflo(unsigned int u) { return __uint_as_float(u << 16); }
__device__ __forceinline__ float bfhi(unsigned int u) { return __uint_as_float(u & 0xffff0000u); }

// ---- fused prep: blocks [0,cgrid) cvt x->bf16 ; blocks [cgrid,..) hist ----
// hist uses 16 replicated count planes (seg = hist-block & 15) to cut
// same-line atomic serialization 16x.
__global__ __launch_bounds__(256) void prep_kernel(
    const float* __restrict__ x, unsigned short* __restrict__ xb, int n8,
    const int* __restrict__ dst, int* __restrict__ counts_rep,
    int* __restrict__ loc, int n_edges, int cgrid, int n_pad)
{
    int tid = threadIdx.x;
    if ((int)blockIdx.x < cgrid) {
        int t = blockIdx.x * 256 + tid;
        if (t >= n8) return;
        const float4* p = reinterpret_cast<const float4*>(x) + (size_t)t * 2;
        float4 v0 = p[0], v1 = p[1];
        uint4 o;
        o.x = bf16r(v0.x) | (bf16r(v0.y) << 16);
        o.y = bf16r(v0.z) | (bf16r(v0.w) << 16);
        o.z = bf16r(v1.x) | (bf16r(v1.y) << 16);
        o.w = bf16r(v1.z) | (bf16r(v1.w) << 16);
        reinterpret_cast<uint4*>(xb)[t] = o;
    } else {
        int hb = blockIdx.x - cgrid;
        int* cp = counts_rep + (size_t)(hb & (NSEG - 1)) * n_pad;
        int t = hb * 256 + tid;
        int e4 = t * 4;
        if (e4 + 4 <= n_edges) {
            int4 d = *reinterpret_cast<const int4*>(dst + e4);
            int4 l;
            l.x = atomicAdd(&cp[d.x], 1);
            l.y = atomicAdd(&cp[d.y], 1);
            l.z = atomicAdd(&cp[d.z], 1);
            l.w = atomicAdd(&cp[d.w], 1);
            *reinterpret_cast<int4*>(loc + e4) = l;
        } else {
            for (int e = e4; e < n_edges; ++e)
                loc[e] = atomicAdd(&cp[dst[e]], 1);
        }
    }
}

// ---- segsum: per node, exclusive prefix across the 16 planes (in place) ---
// counts_rep[s][i] <- sum_{s'<s} counts_rep[s'][i]; counts[i] <- total
__global__ __launch_bounds__(256) void segsum_kernel(
    int* __restrict__ counts_rep, int* __restrict__ counts, int n, int n_pad)
{
    int i = blockIdx.x * 256 + threadIdx.x;
    if (i >= n) return;
    int tot = 0;
    #pragma unroll
    for (int s = 0; s < NSEG; ++s) {
        int* p = counts_rep + (size_t)s * n_pad + i;
        int c = *p;
        *p = tot;
        tot += c;
    }
    counts[i] = tot;
}

// ---------------- fallback tap (f32 in) ------------------------------------
__global__ __launch_bounds__(256) void tap_kernel(
    const float* __restrict__ xin, const float* __restrict__ W,
    const float* __restrict__ b, float* __restrict__ y,
    int n_nodes, int first)
{
    __shared__ float Wt[D * (D + 1)];
    __shared__ float bs[D];
    __shared__ float xs[4][D];

    int tid = threadIdx.x;
    for (int t = tid; t < D * D; t += 256) {
        int j = t >> 6, i = t & 63;
        Wt[i * (D + 1) + j] = W[t];
    }
    if (tid < D) bs[tid] = b[tid];

    int rl = tid >> 6;
    int j  = tid & 63;
    int row = blockIdx.x * 4 + rl;
    if (row < n_nodes) xs[rl][j] = xin[(size_t)row * D + j];
    __syncthreads();

    if (row >= n_nodes) return;

    float acc = bs[j];
    #pragma unroll 8
    for (int i = 0; i < D; ++i)
        acc = fmaf(xs[rl][i], Wt[i * (D + 1) + j], acc);

    float* yp = y + (size_t)row * D + j;
    *yp = first ? acc : (*yp + acc);
}

// ------- tap01: y[row] = x@W0^T + A1@W1^T + (b0+b1)  (write) ---------------
__global__ __launch_bounds__(256) void tap01_kernel(
    const float* __restrict__ x, const unsigned short* __restrict__ A1,
    const float* __restrict__ W, const float* __restrict__ b,
    float* __restrict__ y, int n_nodes)
{
    __shared__ float Wt0[D * (D + 1)];
    __shared__ float Wt1[D * (D + 1)];
    __shared__ float bs[D];
    __shared__ float2 xs[4][D];

    int tid = threadIdx.x;
    for (int t = tid; t < D * D; t += 256) {
        int j = t >> 6, i = t & 63;
        Wt0[i * (D + 1) + j] = W[t];
        Wt1[i * (D + 1) + j] = W[D * D + t];
    }
    if (tid < D) bs[tid] = b[tid] + b[D + tid];
    __syncthreads();

    int w    = tid >> 6;
    int lane = tid & 63;
    int stride = gridDim.x * 4;

    for (int r0 = blockIdx.x * 4; r0 < n_nodes; r0 += stride) {
        int row = r0 + w;
        if (row < n_nodes) {
            size_t o = (size_t)row * D + lane;
            float xv = x[o];
            float a1 = __uint_as_float(((unsigned int)A1[o]) << 16);
            xs[w][lane] = make_float2(xv, a1);          // wave-private slot

            float acc = bs[lane];
            #pragma unroll 16
            for (int i = 0; i < D; ++i) {
                float2 v = xs[w][i];                    // same-addr broadcast
                acc = fmaf(v.x, Wt0[i * (D + 1) + lane],
                      fmaf(v.y, Wt1[i * (D + 1) + lane], acc));
            }
            y[o] = acc;
        }
    }
}

// ------- tap23: y[row] += A2@W2^T + A3@W3^T + (b2+b3)  (RMW) ---------------
__global__ __launch_bounds__(256) void tap23_kernel(
    const unsigned short* __restrict__ A2, const unsigned short* __restrict__ A3,
    const float* __restrict__ W, const float* __restrict__ b,
    float* __restrict__ y, int n_nodes)
{
    __shared__ float Wt2[D * (D + 1)];
    __shared__ float Wt3[D * (D + 1)];
    __shared__ float bs[D];
    __shared__ float2 xs[4][D];

    int tid = threadIdx.x;
    for (int t = tid; t < D * D; t += 256) {
        int j = t >> 6, i = t & 63;
        Wt2[i * (D + 1) + j] = W[2 * D * D + t];
        Wt3[i * (D + 1) + j] = W[3 * D * D + t];
    }
    if (tid < D) bs[tid] = b[2 * D + tid] + b[3 * D + tid];
    __syncthreads();

    int w    = tid >> 6;
    int lane = tid & 63;
    int stride = gridDim.x * 4;

    for (int r0 = blockIdx.x * 4; r0 < n_nodes; r0 += stride) {
        int row = r0 + w;
        if (row < n_nodes) {
            size_t o = (size_t)row * D + lane;
            float a2 = __uint_as_float(((unsigned int)A2[o]) << 16);
            float a3 = __uint_as_float(((unsigned int)A3[o]) << 16);
            xs[w][lane] = make_float2(a2, a3);

            float acc = bs[lane];
            #pragma unroll 16
            for (int i = 0; i < D; ++i) {
                float2 v = xs[w][i];
                acc = fmaf(v.x, Wt2[i * (D + 1) + lane],
                      fmaf(v.y, Wt3[i * (D + 1) + lane], acc));
            }
            y[o] += acc;
        }
    }
}

// ---------------- CSR scan -------------------------------------------------
__global__ __launch_bounds__(256) void scan1_kernel(
    const int* __restrict__ counts, int* __restrict__ excl,
    int* __restrict__ bsum, int n)
{
    __shared__ int lds[256];
    int tid = threadIdx.x;
    int base = blockIdx.x * SCAN_CHUNK + tid * 4;
    int c0 = 0, c1 = 0, c2 = 0, c3 = 0;
    if (base + 3 < n) {
        int4 v = *reinterpret_cast<const int4*>(counts + base);
        c0 = v.x; c1 = v.y; c2 = v.z; c3 = v.w;
    } else {
        if (base + 0 < n) c0 = counts[base + 0];
        if (base + 1 < n) c1 = counts[base + 1];
        if (base + 2 < n) c2 = counts[base + 2];
        if (base + 3 < n) c3 = counts[base + 3];
    }
    int s = c0 + c1 + c2 + c3;
    lds[tid] = s;
    __syncthreads();
    for (int off = 1; off < 256; off <<= 1) {
        int v = (tid >= off) ? lds[tid - off] : 0;
        __syncthreads();
        lds[tid] += v;
        __syncthreads();
    }
    int incl = lds[tid];
    int ex = incl - s;
    if (tid == 255) bsum[blockIdx.x] = incl;
    if (base + 0 < n) excl[base + 0] = ex;
    if (base + 1 < n) excl[base + 1] = ex + c0;
    if (base + 2 < n) excl[base + 2] = ex + c0 + c1;
    if (base + 3 < n) excl[base + 3] = ex + c0 + c1 + c2;
}

// scan3 with in-kernel (redundant per-block) scan of the <=64 block sums
__global__ __launch_bounds__(256) void scan3b_kernel(
    const int* __restrict__ excl, const int* __restrict__ bsum,
    int* __restrict__ rp, int n, int n_edges, int nblk)
{
    __shared__ int sb[64];
    int tid = threadIdx.x;
    if (tid < 64) {
        int v = (tid < nblk) ? bsum[tid] : 0;
        int orig = v;
        for (int off = 1; off < 64; off <<= 1) {
            int t = __shfl_up(v, off);
            if (tid >= off) v += t;
        }
        sb[tid] = v - orig;    // exclusive prefix of block sums
    }
    __syncthreads();
    int i = blockIdx.x * 256 + tid;
    if (i < n) rp[i] = excl[i] + sb[i / SCAN_CHUNK];
    if (i == 0) rp[n] = n_edges;
}

// fill: csr[rp[d] + segbase[seg][d] + loc[e]] = src[e]   (atomic-free)
__global__ __launch_bounds__(256) void fill2_kernel(
    const int* __restrict__ src, const int* __restrict__ dst,
    const int* __restrict__ rp, const int* __restrict__ loc,
    const int* __restrict__ counts_rep,
    int* __restrict__ csr, int n_edges, int n_pad)
{
    const int* segb = counts_rep + (size_t)(blockIdx.x & (NSEG - 1)) * n_pad;
    int t = blockIdx.x * 256 + threadIdx.x;
    int e4 = t * 4;
    if (e4 + 4 <= n_edges) {
        int4 d = *reinterpret_cast<const int4*>(dst + e4);
        int4 s = *reinterpret_cast<const int4*>(src + e4);
        int4 l = *reinterpret_cast<const int4*>(loc + e4);
        csr[rp[d.x] + segb[d.x] + l.x] = s.x;
        csr[rp[d.y] + segb[d.y] + l.y] = s.y;
        csr[rp[d.z] + segb[d.z] + l.z] = s.z;
        csr[rp[d.w] + segb[d.w] + l.w] = s.w;
    } else {
        for (int e = e4; e < n_edges; ++e) {
            int d = dst[e];
            csr[rp[d] + segb[d] + loc[e]] = src[e];
        }
    }
}

// ------- pull (bf16): xout[v] = bf16( sum_{e:dst=v} xin[src[e]] ) ----------
// 2 nodes/wave; 16-lane groups x uint2 => one vmem instr covers 4 rows.
__global__ __launch_bounds__(256) void pull_bf16_kernel(
    const unsigned short* __restrict__ xin, unsigned short* __restrict__ xout,
    const int* __restrict__ rp, const int* __restrict__ csr, int n_nodes)
{
    int tid  = threadIdx.x;
    int wid  = (blockIdx.x * 256 + tid) >> 6;
    int lane = tid & 63;
    int half = lane >> 5;        // node within wave
    int hl   = lane & 31;        // lane within half
    int hb   = half << 5;        // half base
    int g    = (lane >> 4) & 1;  // edge-group within half
    int cl   = lane & 15;        // uint2 chunk within 128B row
    int node = wid * 2 + half;

    int beg = 0, end = 0;
    if (node < n_nodes) { beg = rp[node]; end = rp[node + 1]; }
    int cnt  = end - beg;
    int cntO = __shfl_xor(cnt, 32);
    int maxcnt = cnt > cntO ? cnt : cntO;   // wave-uniform

    const uint2* xu = reinterpret_cast<const uint2*>(xin);
    float a0 = 0.f, a1 = 0.f, a2 = 0.f, a3 = 0.f;

    for (int base = 0; base < maxcnt; base += 32) {
        int t = base + hl;
        int idx = (t < cnt) ? csr[beg + t] : 0;     // coalesced per half-wave
        #pragma unroll
        for (int ii = 0; ii < 8; ++ii) {            // edges 2*ii+g = 0..15
            int el = 2 * ii + g;
            int s = __shfl(idx, hb + el);
            if (base + el < cnt) {
                uint2 u = xu[(size_t)s * 16 + cl];
                a0 += bflo(u.x); a1 += bfhi(u.x);
                a2 += bflo(u.y); a3 += bfhi(u.y);
            }
        }
        if (maxcnt - base > 16) {
            #pragma unroll
            for (int ii = 8; ii < 16; ++ii) {       // edges 16..31
                int el = 2 * ii + g;
                int s = __shfl(idx, hb + el);
                if (base + el < cnt) {
                    uint2 u = xu[(size_t)s * 16 + cl];
                    a0 += bflo(u.x); a1 += bfhi(u.x);
                    a2 += bflo(u.y); a3 += bfhi(u.y);
                }
            }
        }
    }

    // combine the two edge-groups (xor 16 swaps g0<->g1 within each half)
    a0 += __shfl_xor(a0, 16); a1 += __shfl_xor(a1, 16);
    a2 += __shfl_xor(a2, 16); a3 += __shfl_xor(a3, 16);

    if (node < n_nodes && g == 0) {
        uint2 o;
        o.x = bf16r(a0) | (bf16r(a1) << 16);
        o.y = bf16r(a2) | (bf16r(a3) << 16);
        reinterpret_cast<uint2*>(xout)[(size_t)node * 16 + cl] = o;
    }
}

// ---------------- fallback (atomic push) if ws too small -------------------
__global__ __launch_bounds__(256) void scatter_kernel(
    const float* __restrict__ xin, float* __restrict__ xout,
    const int* __restrict__ src, const int* __restrict__ dst, int n_edges)
{
    int t = blockIdx.x * blockDim.x + threadIdx.x;
    int e = t >> 4;
    if (e >= n_edges) return;
    int c = (t & 15) * 4;
    int s = src[e];
    int d = dst[e];
    const float4 v = *reinterpret_cast<const float4*>(xin + (size_t)s * D + c);
    float* o = xout + (size_t)d * D + c;
    atomicAdd(o + 0, v.x);
    atomicAdd(o + 1, v.y);
    atomicAdd(o + 2, v.z);
    atomicAdd(o + 3, v.w);
}

extern "C" void kernel_launch(void* const* d_in, const int* in_sizes, int n_in,
                              void* d_out, int out_size, void* d_ws, size_t ws_size,
                              hipStream_t stream) {
    const float* x  = (const float*)d_in[0];
    const int*   ei = (const int*)d_in[1];
    const float* W  = (const float*)d_in[2];
    const float* b  = (const float*)d_in[3];
    float* y = (float*)d_out;

    int n_nodes = in_sizes[0] / D;   // 50000
    int n_edges = in_sizes[1] / 2;   // 800000
    const int* src = ei;
    const int* dst = ei + n_edges;

    int n_pad = ((n_nodes + SCAN_CHUNK - 1) / SCAN_CHUNK) * SCAN_CHUNK; // 50176
    int nblk  = n_pad / SCAN_CHUNK;                                      // 49

    size_t bufElems = (size_t)n_nodes * D;          // 3.2M
    unsigned short* xb = (unsigned short*)d_ws;     // bf16 x
    unsigned short* Ab = xb + bufElems;             // bf16 agg1
    unsigned short* Bb = Ab + bufElems;             // bf16 agg2
    unsigned short* Cb = Bb + bufElems;             // bf16 agg3
    int* counts_rep = (int*)(Cb + bufElems);        // NSEG planes
    int* counts = counts_rep + (size_t)NSEG * n_pad;
    int* excl   = counts + n_pad;
    int* rp     = excl + n_pad;        // n_nodes+1 used
    int* bsum   = rp + n_pad;          // 64
    int* loc    = bsum + 64;           // n_edges
    int* csr    = loc + n_edges;       // n_edges

    size_t needed = (char*)(csr + n_edges) - (char*)d_ws;

    dim3 tb(256);
    dim3 tg((n_nodes + 3) / 4);
    int e4grid = (n_edges / 4 + 255) / 256;
    int ngrid  = (n_nodes + 255) / 256;
    int n8     = (int)(bufElems / 8);
    int cgrid  = (n8 + 255) / 256;
    int pgrid  = ((n_nodes + 1) / 2 + 3) / 4;   // 2 nodes/wave, 4 waves/block

    if (needed <= ws_size) {
        // ---- prep: memset replicated counts, fused cvt+hist ----
        hipMemsetAsync(counts_rep, 0, (size_t)NSEG * n_pad * sizeof(int), stream);
        prep_kernel<<<cgrid + e4grid, tb, 0, stream>>>(x, xb, n8, dst, counts_rep,
                                                       loc, n_edges, cgrid, n_pad);
        segsum_kernel<<<ngrid, tb, 0, stream>>>(counts_rep, counts, n_nodes, n_pad);
        scan1_kernel<<<nblk, tb, 0, stream>>>(counts, excl, bsum, n_nodes);
        scan3b_kernel<<<ngrid, tb, 0, stream>>>(excl, bsum, rp, n_nodes,
                                                n_edges, nblk);
        fill2_kernel<<<e4grid, tb, 0, stream>>>(src, dst, rp, loc, counts_rep,
                                                csr, n_edges, n_pad);

        // ---- shift chain back-to-back (L2-hot producer->consumer) ----
        pull_bf16_kernel<<<pgrid, tb, 0, stream>>>(xb, Ab, rp, csr, n_nodes);
        pull_bf16_kernel<<<pgrid, tb, 0, stream>>>(Ab, Bb, rp, csr, n_nodes);
        pull_bf16_kernel<<<pgrid, tb, 0, stream>>>(Bb, Cb, rp, csr, n_nodes);

        // ---- tap phase: two 2-tap fused kernels (33KB LDS -> 4 blk/CU) ----
        tap01_kernel<<<1024, tb, 0, stream>>>(x, Ab, W, b, y, n_nodes);
        tap23_kernel<<<1024, tb, 0, stream>>>(Bb, Cb, W, b, y, n_nodes);
    } else {
        // ---- fallback: atomic push path (f32) ----
        float* A = (float*)d_ws;
        float* B = A + bufElems;
        size_t bufBytes = bufElems * sizeof(float);
        int sgrid = (n_edges * 16 + 255) / 256;
        hipMemsetAsync(A, 0, bufBytes, stream);
        hipMemsetAsync(B, 0, bufBytes, stream);
        tap_kernel<<<tg, tb, 0, stream>>>(x, W, b, y, n_nodes, 1);
        scatter_kernel<<<sgrid, tb, 0, stream>>>(x, A, src, dst, n_edges);
        tap_kernel<<<tg, tb, 0, stream>>>(A, W + D * D, b + D, y, n_nodes, 0);
        scatter_kernel<<<sgrid, tb, 0, stream>>>(A, B, src, dst, n_edges);
        hipMemsetAsync(A, 0, bufBytes, stream);
        tap_kernel<<<tg, tb, 0, stream>>>(B, W + 2 * D * D, b + 2 * D, y, n_nodes, 0);
        scatter_kernel<<<sgrid, tb, 0, stream>>>(B, A, src, dst, n_edges);
        tap_kernel<<<tg, tb, 0, stream>>>(A, W + 3 * D * D, b + 3 * D, y, n_nodes, 0);
    }
}

// Round 11
// 158.174 us; speedup vs baseline: 1.5907x; 1.3804x over previous
//
#include <hip/hip_runtime.h>

#define D 64
#define SCAN_CHUNK 1024   // elements per scan1 block (256 thr x 4)
#define NSEG 16           // histogram replicas (contention divider)

typedef __attribute__((ext_vector_type(8))) short bf16x8;   // 8 bf16 (4 VGPRs)
typedef __attribute__((ext_vector_type(4))) float f32x4;    // 4 f32 acc

__device__ __forceinline__ unsigned int bf16r(float f) {
    unsigned int u = __float_as_uint(f);
    return (u + 0x7fffu + ((u >> 16) & 1u)) >> 16;   // RNE to bf16
}
__device__ __forceinline__ float bflo(unsigned int u) { return __uint_as_float(u << 16); }
__device__ __forceinline__ float bfhi(unsigned int u) { return __uint_as_float(u & 0xffff0000u); }

// ---- fused prep: [0,cgrid) cvt x->bf16 ; [cgrid,cgrid+wgrid) cvt W->bf16 ;
//      rest: replicated histogram of dst (seg = hist-block & 15) ------------
__global__ __launch_bounds__(256) void prep_kernel(
    const float* __restrict__ x, unsigned short* __restrict__ xb, int n8,
    const float* __restrict__ W, unsigned short* __restrict__ Wb, int w8,
    const int* __restrict__ dst, int* __restrict__ counts_rep,
    int* __restrict__ loc, int n_edges, int cgrid, int wgrid, int n_pad)
{
    int tid = threadIdx.x;
    int bi = blockIdx.x;
    if (bi < cgrid + wgrid) {
        const float* in; unsigned short* out; int t;
        if (bi < cgrid) { in = x; out = xb; t = bi * 256 + tid; if (t >= n8) return; }
        else            { in = W; out = Wb; t = (bi - cgrid) * 256 + tid; if (t >= w8) return; }
        const float4* p = reinterpret_cast<const float4*>(in) + (size_t)t * 2;
        float4 v0 = p[0], v1 = p[1];
        uint4 o;
        o.x = bf16r(v0.x) | (bf16r(v0.y) << 16);
        o.y = bf16r(v0.z) | (bf16r(v0.w) << 16);
        o.z = bf16r(v1.x) | (bf16r(v1.y) << 16);
        o.w = bf16r(v1.z) | (bf16r(v1.w) << 16);
        reinterpret_cast<uint4*>(out)[t] = o;
    } else {
        int hb = bi - cgrid - wgrid;
        int* cp = counts_rep + (size_t)(hb & (NSEG - 1)) * n_pad;
        int t = hb * 256 + tid;
        int e4 = t * 4;
        if (e4 + 4 <= n_edges) {
            int4 d = *reinterpret_cast<const int4*>(dst + e4);
            int4 l;
            l.x = atomicAdd(&cp[d.x], 1);
            l.y = atomicAdd(&cp[d.y], 1);
            l.z = atomicAdd(&cp[d.z], 1);
            l.w = atomicAdd(&cp[d.w], 1);
            *reinterpret_cast<int4*>(loc + e4) = l;
        } else {
            for (int e = e4; e < n_edges; ++e)
                loc[e] = atomicAdd(&cp[dst[e]], 1);
        }
    }
}

// ---- segsum: per node, exclusive prefix across the 16 planes (in place) ---
__global__ __launch_bounds__(256) void segsum_kernel(
    int* __restrict__ counts_rep, int* __restrict__ counts, int n, int n_pad)
{
    int i = blockIdx.x * 256 + threadIdx.x;
    if (i >= n) return;
    int tot = 0;
    #pragma unroll
    for (int s = 0; s < NSEG; ++s) {
        int* p = counts_rep + (size_t)s * n_pad + i;
        int c = *p;
        *p = tot;
        tot += c;
    }
    counts[i] = tot;
}

// ---------------- fallback tap (f32 in) ------------------------------------
__global__ __launch_bounds__(256) void tap_kernel(
    const float* __restrict__ xin, const float* __restrict__ W,
    const float* __restrict__ b, float* __restrict__ y,
    int n_nodes, int first)
{
    __shared__ float Wt[D * (D + 1)];
    __shared__ float bs[D];
    __shared__ float xs[4][D];

    int tid = threadIdx.x;
    for (int t = tid; t < D * D; t += 256) {
        int j = t >> 6, i = t & 63;
        Wt[i * (D + 1) + j] = W[t];
    }
    if (tid < D) bs[tid] = b[tid];

    int rl = tid >> 6;
    int j  = tid & 63;
    int row = blockIdx.x * 4 + rl;
    if (row < n_nodes) xs[rl][j] = xin[(size_t)row * D + j];
    __syncthreads();

    if (row >= n_nodes) return;

    float acc = bs[j];
    #pragma unroll 8
    for (int i = 0; i < D; ++i)
        acc = fmaf(xs[rl][i], Wt[i * (D + 1) + j], acc);

    float* yp = y + (size_t)row * D + j;
    *yp = first ? acc : (*yp + acc);
}

// ------- MFMA fused tap: y = [X0|X1|X2|X3](bf16) @ Wcat^T + sum_b ----------
// One wave per 16-row tile. A: row=lane&15, k=(lane>>4)*8+j (16B/lane).
// B[k][col]=W[col][k]: lane reads 8 contiguous elems of W row (jt*16+lane&15).
// C/D (m89): col=lane&15, row=(lane>>4)*4+reg.
__global__ __launch_bounds__(256) void mfma_tap_kernel(
    const unsigned short* __restrict__ X0, const unsigned short* __restrict__ X1,
    const unsigned short* __restrict__ X2, const unsigned short* __restrict__ X3,
    const unsigned short* __restrict__ Wb, const float* __restrict__ b,
    float* __restrict__ y, int n_tiles)
{
    int wv   = threadIdx.x >> 6;
    int lane = threadIdx.x & 63;
    int tile = blockIdx.x * 4 + wv;
    if (tile >= n_tiles) return;

    int col = lane & 15;
    int kg  = lane >> 4;          // K-group 0..3

    f32x4 acc[4];
    #pragma unroll
    for (int jt = 0; jt < 4; ++jt) {
        int c = jt * 16 + col;
        float bias = b[c] + b[64 + c] + b[128 + c] + b[192 + c];
        acc[jt] = (f32x4){bias, bias, bias, bias};
    }

    const unsigned short* Xs[4] = {X0, X1, X2, X3};
    size_t arow = (size_t)(tile * 16 + col) * D + kg * 8;

    #pragma unroll
    for (int m = 0; m < 4; ++m) {
        const unsigned short* Xm = Xs[m];
        #pragma unroll
        for (int s = 0; s < 2; ++s) {
            bf16x8 a = *reinterpret_cast<const bf16x8*>(Xm + arow + s * 32);
            #pragma unroll
            for (int jt = 0; jt < 4; ++jt) {
                bf16x8 bb = *reinterpret_cast<const bf16x8*>(
                    Wb + m * 4096 + (jt * 16 + col) * D + s * 32 + kg * 8);
                acc[jt] = __builtin_amdgcn_mfma_f32_16x16x32_bf16(a, bb, acc[jt], 0, 0, 0);
            }
        }
    }

    #pragma unroll
    for (int jt = 0; jt < 4; ++jt) {
        #pragma unroll
        for (int r = 0; r < 4; ++r) {
            int row = kg * 4 + r;
            y[(size_t)(tile * 16 + row) * D + jt * 16 + col] = acc[jt][r];
        }
    }
}

// ---------------- CSR scan -------------------------------------------------
__global__ __launch_bounds__(256) void scan1_kernel(
    const int* __restrict__ counts, int* __restrict__ excl,
    int* __restrict__ bsum, int n)
{
    __shared__ int lds[256];
    int tid = threadIdx.x;
    int base = blockIdx.x * SCAN_CHUNK + tid * 4;
    int c0 = 0, c1 = 0, c2 = 0, c3 = 0;
    if (base + 3 < n) {
        int4 v = *reinterpret_cast<const int4*>(counts + base);
        c0 = v.x; c1 = v.y; c2 = v.z; c3 = v.w;
    } else {
        if (base + 0 < n) c0 = counts[base + 0];
        if (base + 1 < n) c1 = counts[base + 1];
        if (base + 2 < n) c2 = counts[base + 2];
        if (base + 3 < n) c3 = counts[base + 3];
    }
    int s = c0 + c1 + c2 + c3;
    lds[tid] = s;
    __syncthreads();
    for (int off = 1; off < 256; off <<= 1) {
        int v = (tid >= off) ? lds[tid - off] : 0;
        __syncthreads();
        lds[tid] += v;
        __syncthreads();
    }
    int incl = lds[tid];
    int ex = incl - s;
    if (tid == 255) bsum[blockIdx.x] = incl;
    if (base + 0 < n) excl[base + 0] = ex;
    if (base + 1 < n) excl[base + 1] = ex + c0;
    if (base + 2 < n) excl[base + 2] = ex + c0 + c1;
    if (base + 3 < n) excl[base + 3] = ex + c0 + c1 + c2;
}

// scan3 with in-kernel (redundant per-block) scan of the <=64 block sums
__global__ __launch_bounds__(256) void scan3b_kernel(
    const int* __restrict__ excl, const int* __restrict__ bsum,
    int* __restrict__ rp, int n, int n_edges, int nblk)
{
    __shared__ int sb[64];
    int tid = threadIdx.x;
    if (tid < 64) {
        int v = (tid < nblk) ? bsum[tid] : 0;
        int orig = v;
        for (int off = 1; off < 64; off <<= 1) {
            int t = __shfl_up(v, off);
            if (tid >= off) v += t;
        }
        sb[tid] = v - orig;    // exclusive prefix of block sums
    }
    __syncthreads();
    int i = blockIdx.x * 256 + tid;
    if (i < n) rp[i] = excl[i] + sb[i / SCAN_CHUNK];
    if (i == 0) rp[n] = n_edges;
}

// fill: csr[rp[d] + segbase[seg][d] + loc[e]] = src[e]   (atomic-free)
__global__ __launch_bounds__(256) void fill2_kernel(
    const int* __restrict__ src, const int* __restrict__ dst,
    const int* __restrict__ rp, const int* __restrict__ loc,
    const int* __restrict__ counts_rep,
    int* __restrict__ csr, int n_edges, int n_pad)
{
    const int* segb = counts_rep + (size_t)(blockIdx.x & (NSEG - 1)) * n_pad;
    int t = blockIdx.x * 256 + threadIdx.x;
    int e4 = t * 4;
    if (e4 + 4 <= n_edges) {
        int4 d = *reinterpret_cast<const int4*>(dst + e4);
        int4 s = *reinterpret_cast<const int4*>(src + e4);
        int4 l = *reinterpret_cast<const int4*>(loc + e4);
        csr[rp[d.x] + segb[d.x] + l.x] = s.x;
        csr[rp[d.y] + segb[d.y] + l.y] = s.y;
        csr[rp[d.z] + segb[d.z] + l.z] = s.z;
        csr[rp[d.w] + segb[d.w] + l.w] = s.w;
    } else {
        for (int e = e4; e < n_edges; ++e) {
            int d = dst[e];
            csr[rp[d] + segb[d] + loc[e]] = src[e];
        }
    }
}

// ------- pull (bf16): xout[v] = bf16( sum_{e:dst=v} xin[src[e]] ) ----------
__global__ __launch_bounds__(256) void pull_bf16_kernel(
    const unsigned short* __restrict__ xin, unsigned short* __restrict__ xout,
    const int* __restrict__ rp, const int* __restrict__ csr, int n_nodes)
{
    int tid  = threadIdx.x;
    int wid  = (blockIdx.x * 256 + tid) >> 6;
    int lane = tid & 63;
    int half = lane >> 5;        // node within wave
    int hl   = lane & 31;        // lane within half
    int hb   = half << 5;        // half base
    int g    = (lane >> 4) & 1;  // edge-group within half
    int cl   = lane & 15;        // uint2 chunk within 128B row
    int node = wid * 2 + half;

    int beg = 0, end = 0;
    if (node < n_nodes) { beg = rp[node]; end = rp[node + 1]; }
    int cnt  = end - beg;
    int cntO = __shfl_xor(cnt, 32);
    int maxcnt = cnt > cntO ? cnt : cntO;   // wave-uniform

    const uint2* xu = reinterpret_cast<const uint2*>(xin);
    float a0 = 0.f, a1 = 0.f, a2 = 0.f, a3 = 0.f;

    for (int base = 0; base < maxcnt; base += 32) {
        int t = base + hl;
        int idx = (t < cnt) ? csr[beg + t] : 0;     // coalesced per half-wave
        #pragma unroll
        for (int ii = 0; ii < 8; ++ii) {            // edges 2*ii+g = 0..15
            int el = 2 * ii + g;
            int s = __shfl(idx, hb + el);
            if (base + el < cnt) {
                uint2 u = xu[(size_t)s * 16 + cl];
                a0 += bflo(u.x); a1 += bfhi(u.x);
                a2 += bflo(u.y); a3 += bfhi(u.y);
            }
        }
        if (maxcnt - base > 16) {
            #pragma unroll
            for (int ii = 8; ii < 16; ++ii) {       // edges 16..31
                int el = 2 * ii + g;
                int s = __shfl(idx, hb + el);
                if (base + el < cnt) {
                    uint2 u = xu[(size_t)s * 16 + cl];
                    a0 += bflo(u.x); a1 += bfhi(u.x);
                    a2 += bflo(u.y); a3 += bfhi(u.y);
                }
            }
        }
    }

    a0 += __shfl_xor(a0, 16); a1 += __shfl_xor(a1, 16);
    a2 += __shfl_xor(a2, 16); a3 += __shfl_xor(a3, 16);

    if (node < n_nodes && g == 0) {
        uint2 o;
        o.x = bf16r(a0) | (bf16r(a1) << 16);
        o.y = bf16r(a2) | (bf16r(a3) << 16);
        reinterpret_cast<uint2*>(xout)[(size_t)node * 16 + cl] = o;
    }
}

// ---------------- fallback (atomic push) if ws too small -------------------
__global__ __launch_bounds__(256) void scatter_kernel(
    const float* __restrict__ xin, float* __restrict__ xout,
    const int* __restrict__ src, const int* __restrict__ dst, int n_edges)
{
    int t = blockIdx.x * blockDim.x + threadIdx.x;
    int e = t >> 4;
    if (e >= n_edges) return;
    int c = (t & 15) * 4;
    int s = src[e];
    int d = dst[e];
    const float4 v = *reinterpret_cast<const float4*>(xin + (size_t)s * D + c);
    float* o = xout + (size_t)d * D + c;
    atomicAdd(o + 0, v.x);
    atomicAdd(o + 1, v.y);
    atomicAdd(o + 2, v.z);
    atomicAdd(o + 3, v.w);
}

extern "C" void kernel_launch(void* const* d_in, const int* in_sizes, int n_in,
                              void* d_out, int out_size, void* d_ws, size_t ws_size,
                              hipStream_t stream) {
    const float* x  = (const float*)d_in[0];
    const int*   ei = (const int*)d_in[1];
    const float* W  = (const float*)d_in[2];
    const float* b  = (const float*)d_in[3];
    float* y = (float*)d_out;

    int n_nodes = in_sizes[0] / D;   // 50000
    int n_edges = in_sizes[1] / 2;   // 800000
    const int* src = ei;
    const int* dst = ei + n_edges;

    int n_pad = ((n_nodes + SCAN_CHUNK - 1) / SCAN_CHUNK) * SCAN_CHUNK; // 50176
    int nblk  = n_pad / SCAN_CHUNK;                                      // 49

    size_t bufElems = (size_t)n_nodes * D;          // 3.2M
    unsigned short* xb = (unsigned short*)d_ws;     // bf16 x
    unsigned short* Ab = xb + bufElems;             // bf16 agg1
    unsigned short* Bb = Ab + bufElems;             // bf16 agg2
    unsigned short* Cb = Bb + bufElems;             // bf16 agg3
    unsigned short* Wb = Cb + bufElems;             // bf16 W (4*64*64)
    int* counts_rep = (int*)(Wb + 4 * D * D);       // NSEG planes
    int* counts = counts_rep + (size_t)NSEG * n_pad;
    int* excl   = counts + n_pad;
    int* rp     = excl + n_pad;        // n_nodes+1 used
    int* bsum   = rp + n_pad;          // 64
    int* loc    = bsum + 64;           // n_edges
    int* csr    = loc + n_edges;       // n_edges

    size_t needed = (char*)(csr + n_edges) - (char*)d_ws;

    dim3 tb(256);
    dim3 tg((n_nodes + 3) / 4);
    int e4grid = (n_edges / 4 + 255) / 256;
    int ngrid  = (n_nodes + 255) / 256;
    int n8     = (int)(bufElems / 8);
    int cgrid  = (n8 + 255) / 256;
    int w8     = 4 * D * D / 8;                 // 2048
    int wgrid  = (w8 + 255) / 256;              // 8
    int pgrid  = ((n_nodes + 1) / 2 + 3) / 4;   // 2 nodes/wave, 4 waves/block
    int n_tiles = (n_nodes + 15) / 16;          // 3125
    int mgrid  = (n_tiles + 3) / 4;

    if (needed <= ws_size && (n_nodes & 15) == 0) {
        // ---- prep: memset replicated counts, fused cvt(x,W)+hist ----
        hipMemsetAsync(counts_rep, 0, (size_t)NSEG * n_pad * sizeof(int), stream);
        prep_kernel<<<cgrid + wgrid + e4grid, tb, 0, stream>>>(
            x, xb, n8, W, Wb, w8, dst, counts_rep, loc, n_edges, cgrid, wgrid, n_pad);
        segsum_kernel<<<ngrid, tb, 0, stream>>>(counts_rep, counts, n_nodes, n_pad);
        scan1_kernel<<<nblk, tb, 0, stream>>>(counts, excl, bsum, n_nodes);
        scan3b_kernel<<<ngrid, tb, 0, stream>>>(excl, bsum, rp, n_nodes,
                                                n_edges, nblk);
        fill2_kernel<<<e4grid, tb, 0, stream>>>(src, dst, rp, loc, counts_rep,
                                                csr, n_edges, n_pad);

        // ---- shift chain back-to-back (L2-hot producer->consumer) ----
        pull_bf16_kernel<<<pgrid, tb, 0, stream>>>(xb, Ab, rp, csr, n_nodes);
        pull_bf16_kernel<<<pgrid, tb, 0, stream>>>(Ab, Bb, rp, csr, n_nodes);
        pull_bf16_kernel<<<pgrid, tb, 0, stream>>>(Bb, Cb, rp, csr, n_nodes);

        // ---- tap phase: single MFMA GEMM  y = Xcat @ Wcat^T + bsum ----
        mfma_tap_kernel<<<mgrid, tb, 0, stream>>>(xb, Ab, Bb, Cb, Wb, b, y, n_tiles);
    } else {
        // ---- fallback: atomic push path (f32) ----
        float* A = (float*)d_ws;
        float* B = A + bufElems;
        size_t bufBytes = bufElems * sizeof(float);
        int sgrid = (n_edges * 16 + 255) / 256;
        hipMemsetAsync(A, 0, bufBytes, stream);
        hipMemsetAsync(B, 0, bufBytes, stream);
        tap_kernel<<<tg, tb, 0, stream>>>(x, W, b, y, n_nodes, 1);
        scatter_kernel<<<sgrid, tb, 0, stream>>>(x, A, src, dst, n_edges);
        tap_kernel<<<tg, tb, 0, stream>>>(A, W + D * D, b + D, y, n_nodes, 0);
        scatter_kernel<<<sgrid, tb, 0, stream>>>(A, B, src, dst, n_edges);
        hipMemsetAsync(A, 0, bufBytes, stream);
        tap_kernel<<<tg, tb, 0, stream>>>(B, W + 2 * D * D, b + 2 * D, y, n_nodes, 0);
        scatter_kernel<<<sgrid, tb, 0, stream>>>(B, A, src, dst, n_edges);
        tap_kernel<<<tg, tb, 0, stream>>>(A, W + 3 * D * D, b + 3 * D, y, n_nodes, 0);
    }
}

// Round 12
// 133.985 us; speedup vs baseline: 1.8779x; 1.1805x over previous
//
#include <hip/hip_runtime.h>

#define D 64
#define NB 1024        // nodes per dst-bucket
#define NBK_MAX 64
#define BCAP 20480     // edge capacity per bucket (avg 16.3k, +32 sigma)

typedef __attribute__((ext_vector_type(8))) short bf16x8;   // 8 bf16 (4 VGPRs)
typedef __attribute__((ext_vector_type(4))) float f32x4;    // 4 f32 acc

__device__ __forceinline__ unsigned int bf16r(float f) {
    unsigned int u = __float_as_uint(f);
    return (u + 0x7fffu + ((u >> 16) & 1u)) >> 16;   // RNE to bf16
}
__device__ __forceinline__ float bflo(unsigned int u) { return __uint_as_float(u << 16); }
__device__ __forceinline__ float bfhi(unsigned int u) { return __uint_as_float(u & 0xffff0000u); }

// ---- P1: [0,cgrid) cvt x->bf16 ; [cgrid,+wgrid) cvt W->bf16 ;
//      rest: partition edges into dst-buckets via LDS histogram ------------
__global__ __launch_bounds__(256) void p1_kernel(
    const float* __restrict__ x, unsigned short* __restrict__ xb, int n8,
    const float* __restrict__ W, unsigned short* __restrict__ Wb, int w8,
    const int* __restrict__ src, const int* __restrict__ dst, int n_edges,
    int* __restrict__ bcursor, int* __restrict__ bpack, int nbk,
    int cgrid, int wgrid)
{
    __shared__ int lh[NBK_MAX * 8];     // 8 replicas per bucket
    __shared__ int lbase[NBK_MAX * 8];

    int tid = threadIdx.x;
    int bi  = blockIdx.x;

    if (bi < cgrid + wgrid) {
        const float* in; unsigned short* out; int t;
        if (bi < cgrid) { in = x; out = xb; t = bi * 256 + tid; if (t >= n8) return; }
        else            { in = W; out = Wb; t = (bi - cgrid) * 256 + tid; if (t >= w8) return; }
        const float4* p = reinterpret_cast<const float4*>(in) + (size_t)t * 2;
        float4 v0 = p[0], v1 = p[1];
        uint4 o;
        o.x = bf16r(v0.x) | (bf16r(v0.y) << 16);
        o.y = bf16r(v0.z) | (bf16r(v0.w) << 16);
        o.z = bf16r(v1.x) | (bf16r(v1.y) << 16);
        o.w = bf16r(v1.z) | (bf16r(v1.w) << 16);
        reinterpret_cast<uint4*>(out)[t] = o;
        return;
    }

    // ---- partition: this block owns 1024 edges ----
    for (int t = tid; t < NBK_MAX * 8; t += 256) lh[t] = 0;
    __syncthreads();

    int pb = bi - cgrid - wgrid;
    int e4 = pb * 1024 + tid * 4;
    int r  = tid & 7;

    int dv[4], sv[4], bk[4], lo[4];
    bool ok[4];
    if (e4 + 4 <= n_edges) {
        int4 dd = *reinterpret_cast<const int4*>(dst + e4);
        int4 ss = *reinterpret_cast<const int4*>(src + e4);
        dv[0] = dd.x; dv[1] = dd.y; dv[2] = dd.z; dv[3] = dd.w;
        sv[0] = ss.x; sv[1] = ss.y; sv[2] = ss.z; sv[3] = ss.w;
        ok[0] = ok[1] = ok[2] = ok[3] = true;
    } else {
        #pragma unroll
        for (int j = 0; j < 4; ++j) {
            ok[j] = (e4 + j < n_edges);
            dv[j] = ok[j] ? dst[e4 + j] : 0;
            sv[j] = ok[j] ? src[e4 + j] : 0;
        }
    }
    #pragma unroll
    for (int j = 0; j < 4; ++j) {
        bk[j] = dv[j] >> 10;
        if (ok[j]) lo[j] = atomicAdd(&lh[(bk[j] << 3) | r], 1);
    }
    __syncthreads();

    if (tid < nbk) {
        int tot = 0, pbs[8];
        #pragma unroll
        for (int rr = 0; rr < 8; ++rr) { pbs[rr] = tot; tot += lh[(tid << 3) | rr]; }
        int gb = atomicAdd(&bcursor[tid], tot);      // 49 global atomics/block
        #pragma unroll
        for (int rr = 0; rr < 8; ++rr) lbase[(tid << 3) | rr] = gb + pbs[rr];
    }
    __syncthreads();

    #pragma unroll
    for (int j = 0; j < 4; ++j) {
        if (ok[j]) {
            int pos = lbase[(bk[j] << 3) | r] + lo[j];
            bpack[bk[j] * BCAP + pos] = sv[j] | ((dv[j] & (NB - 1)) << 20);
        }
    }
}

// ---- P2: per-bucket CSR (LDS count -> scan -> rp, then LDS-cursor fill) ---
__global__ __launch_bounds__(1024) void p2_kernel(
    const int* __restrict__ bcursor, const int* __restrict__ bpack,
    int* __restrict__ rp, int* __restrict__ csr,
    int n_nodes, int n_edges, int nbk)
{
    __shared__ int sz[NBK_MAX];
    __shared__ int lh[NB];
    __shared__ int ls[NB];

    int tid = threadIdx.x;
    int bk  = blockIdx.x;

    if (tid < NBK_MAX) sz[tid] = (tid < nbk) ? bcursor[tid] : 0;
    lh[tid] = 0;
    __syncthreads();
    if (tid == 0) {                      // tiny serial prefix of 49 sizes
        int a = 0;
        for (int i = 0; i < nbk; ++i) { int c = sz[i]; sz[i] = a; a += c; }
    }
    __syncthreads();

    int cnt      = bcursor[bk];
    int csr_base = sz[bk];
    const int* bp = bpack + (size_t)bk * BCAP;

    // count
    for (int i = tid; i < cnt; i += 1024) atomicAdd(&lh[bp[i] >> 20], 1);
    __syncthreads();

    // exclusive scan of 1024 bins
    int v = lh[tid];
    ls[tid] = v;
    __syncthreads();
    for (int off = 1; off < 1024; off <<= 1) {
        int t = (tid >= off) ? ls[tid - off] : 0;
        __syncthreads();
        ls[tid] += t;
        __syncthreads();
    }
    int ex = ls[tid] - v;

    int node = bk * NB + tid;
    if (node < n_nodes) rp[node] = csr_base + ex;
    if (bk == nbk - 1 && tid == 0) rp[n_nodes] = n_edges;
    __syncthreads();

    lh[tid] = ex;                        // reuse as cursor
    __syncthreads();
    for (int i = tid; i < cnt; i += 1024) {
        int p = bp[i];
        int pos = atomicAdd(&lh[p >> 20], 1);
        csr[csr_base + pos] = p & 0xFFFFF;
    }
}

// ---------------- fallback tap (f32 in) ------------------------------------
__global__ __launch_bounds__(256) void tap_kernel(
    const float* __restrict__ xin, const float* __restrict__ W,
    const float* __restrict__ b, float* __restrict__ y,
    int n_nodes, int first)
{
    __shared__ float Wt[D * (D + 1)];
    __shared__ float bs[D];
    __shared__ float xs[4][D];

    int tid = threadIdx.x;
    for (int t = tid; t < D * D; t += 256) {
        int j = t >> 6, i = t & 63;
        Wt[i * (D + 1) + j] = W[t];
    }
    if (tid < D) bs[tid] = b[tid];

    int rl = tid >> 6;
    int j  = tid & 63;
    int row = blockIdx.x * 4 + rl;
    if (row < n_nodes) xs[rl][j] = xin[(size_t)row * D + j];
    __syncthreads();

    if (row >= n_nodes) return;

    float acc = bs[j];
    #pragma unroll 8
    for (int i = 0; i < D; ++i)
        acc = fmaf(xs[rl][i], Wt[i * (D + 1) + j], acc);

    float* yp = y + (size_t)row * D + j;
    *yp = first ? acc : (*yp + acc);
}

// ------- MFMA fused tap: y = [X0|X1|X2|X3](bf16) @ Wcat^T + sum_b ----------
__global__ __launch_bounds__(256) void mfma_tap_kernel(
    const unsigned short* __restrict__ X0, const unsigned short* __restrict__ X1,
    const unsigned short* __restrict__ X2, const unsigned short* __restrict__ X3,
    const unsigned short* __restrict__ Wb, const float* __restrict__ b,
    float* __restrict__ y, int n_tiles)
{
    int wv   = threadIdx.x >> 6;
    int lane = threadIdx.x & 63;
    int tile = blockIdx.x * 4 + wv;
    if (tile >= n_tiles) return;

    int col = lane & 15;
    int kg  = lane >> 4;          // K-group 0..3

    f32x4 acc[4];
    #pragma unroll
    for (int jt = 0; jt < 4; ++jt) {
        int c = jt * 16 + col;
        float bias = b[c] + b[64 + c] + b[128 + c] + b[192 + c];
        acc[jt] = (f32x4){bias, bias, bias, bias};
    }

    const unsigned short* Xs[4] = {X0, X1, X2, X3};
    size_t arow = (size_t)(tile * 16 + col) * D + kg * 8;

    #pragma unroll
    for (int m = 0; m < 4; ++m) {
        const unsigned short* Xm = Xs[m];
        #pragma unroll
        for (int s = 0; s < 2; ++s) {
            bf16x8 a = *reinterpret_cast<const bf16x8*>(Xm + arow + s * 32);
            #pragma unroll
            for (int jt = 0; jt < 4; ++jt) {
                bf16x8 bb = *reinterpret_cast<const bf16x8*>(
                    Wb + m * 4096 + (jt * 16 + col) * D + s * 32 + kg * 8);
                acc[jt] = __builtin_amdgcn_mfma_f32_16x16x32_bf16(a, bb, acc[jt], 0, 0, 0);
            }
        }
    }

    #pragma unroll
    for (int jt = 0; jt < 4; ++jt) {
        #pragma unroll
        for (int r = 0; r < 4; ++r) {
            int row = kg * 4 + r;
            y[(size_t)(tile * 16 + row) * D + jt * 16 + col] = acc[jt][r];
        }
    }
}

// ------- pull (bf16): xout[v] = bf16( sum_{e:dst=v} xin[src[e]] ) ----------
__global__ __launch_bounds__(256) void pull_bf16_kernel(
    const unsigned short* __restrict__ xin, unsigned short* __restrict__ xout,
    const int* __restrict__ rp, const int* __restrict__ csr, int n_nodes)
{
    int tid  = threadIdx.x;
    int wid  = (blockIdx.x * 256 + tid) >> 6;
    int lane = tid & 63;
    int half = lane >> 5;        // node within wave
    int hl   = lane & 31;        // lane within half
    int hb   = half << 5;        // half base
    int g    = (lane >> 4) & 1;  // edge-group within half
    int cl   = lane & 15;        // uint2 chunk within 128B row
    int node = wid * 2 + half;

    int beg = 0, end = 0;
    if (node < n_nodes) { beg = rp[node]; end = rp[node + 1]; }
    int cnt  = end - beg;
    int cntO = __shfl_xor(cnt, 32);
    int maxcnt = cnt > cntO ? cnt : cntO;   // wave-uniform

    const uint2* xu = reinterpret_cast<const uint2*>(xin);
    float a0 = 0.f, a1 = 0.f, a2 = 0.f, a3 = 0.f;

    for (int base = 0; base < maxcnt; base += 32) {
        int t = base + hl;
        int idx = (t < cnt) ? csr[beg + t] : 0;     // coalesced per half-wave
        #pragma unroll
        for (int ii = 0; ii < 8; ++ii) {            // edges 2*ii+g = 0..15
            int el = 2 * ii + g;
            int s = __shfl(idx, hb + el);
            if (base + el < cnt) {
                uint2 u = xu[(size_t)s * 16 + cl];
                a0 += bflo(u.x); a1 += bfhi(u.x);
                a2 += bflo(u.y); a3 += bfhi(u.y);
            }
        }
        if (maxcnt - base > 16) {
            #pragma unroll
            for (int ii = 8; ii < 16; ++ii) {       // edges 16..31
                int el = 2 * ii + g;
                int s = __shfl(idx, hb + el);
                if (base + el < cnt) {
                    uint2 u = xu[(size_t)s * 16 + cl];
                    a0 += bflo(u.x); a1 += bfhi(u.x);
                    a2 += bflo(u.y); a3 += bfhi(u.y);
                }
            }
        }
    }

    a0 += __shfl_xor(a0, 16); a1 += __shfl_xor(a1, 16);
    a2 += __shfl_xor(a2, 16); a3 += __shfl_xor(a3, 16);

    if (node < n_nodes && g == 0) {
        uint2 o;
        o.x = bf16r(a0) | (bf16r(a1) << 16);
        o.y = bf16r(a2) | (bf16r(a3) << 16);
        reinterpret_cast<uint2*>(xout)[(size_t)node * 16 + cl] = o;
    }
}

// ---------------- fallback (atomic push) if ws too small -------------------
__global__ __launch_bounds__(256) void scatter_kernel(
    const float* __restrict__ xin, float* __restrict__ xout,
    const int* __restrict__ src, const int* __restrict__ dst, int n_edges)
{
    int t = blockIdx.x * blockDim.x + threadIdx.x;
    int e = t >> 4;
    if (e >= n_edges) return;
    int c = (t & 15) * 4;
    int s = src[e];
    int d = dst[e];
    const float4 v = *reinterpret_cast<const float4*>(xin + (size_t)s * D + c);
    float* o = xout + (size_t)d * D + c;
    atomicAdd(o + 0, v.x);
    atomicAdd(o + 1, v.y);
    atomicAdd(o + 2, v.z);
    atomicAdd(o + 3, v.w);
}

extern "C" void kernel_launch(void* const* d_in, const int* in_sizes, int n_in,
                              void* d_out, int out_size, void* d_ws, size_t ws_size,
                              hipStream_t stream) {
    const float* x  = (const float*)d_in[0];
    const int*   ei = (const int*)d_in[1];
    const float* W  = (const float*)d_in[2];
    const float* b  = (const float*)d_in[3];
    float* y = (float*)d_out;

    int n_nodes = in_sizes[0] / D;   // 50000
    int n_edges = in_sizes[1] / 2;   // 800000
    const int* src = ei;
    const int* dst = ei + n_edges;

    int nbk = (n_nodes + NB - 1) / NB;               // 49

    size_t bufElems = (size_t)n_nodes * D;          // 3.2M
    unsigned short* xb = (unsigned short*)d_ws;     // bf16 x
    unsigned short* Ab = xb + bufElems;             // bf16 agg1
    unsigned short* Bb = Ab + bufElems;             // bf16 agg2
    unsigned short* Cb = Bb + bufElems;             // bf16 agg3
    unsigned short* Wb = Cb + bufElems;             // bf16 W (4*64*64)
    int* bcursor = (int*)(Wb + 4 * D * D);          // NBK_MAX
    int* bpack   = bcursor + NBK_MAX;               // nbk*BCAP packed edges
    int* rp      = bpack + (size_t)nbk * BCAP;      // n_nodes+1 (+pad)
    int* csr     = rp + n_nodes + 64;               // n_edges

    size_t needed = (char*)(csr + n_edges) - (char*)d_ws;

    dim3 tb(256);
    dim3 tg((n_nodes + 3) / 4);
    int n8     = (int)(bufElems / 8);
    int cgrid  = (n8 + 255) / 256;
    int w8     = 4 * D * D / 8;                 // 2048
    int wgrid  = (w8 + 255) / 256;              // 8
    int eb     = (n_edges + 1023) / 1024;       // 782
    int pgrid  = ((n_nodes + 1) / 2 + 3) / 4;   // 2 nodes/wave, 4 waves/block
    int n_tiles = (n_nodes + 15) / 16;          // 3125
    int mgrid  = (n_tiles + 3) / 4;

    if (needed <= ws_size && (n_nodes & 15) == 0 && nbk <= NBK_MAX) {
        // ---- CSR build: P1 (fused cvt + bucket partition) then P2 ----
        hipMemsetAsync(bcursor, 0, NBK_MAX * sizeof(int), stream);
        p1_kernel<<<cgrid + wgrid + eb, tb, 0, stream>>>(
            x, xb, n8, W, Wb, w8, src, dst, n_edges, bcursor, bpack, nbk,
            cgrid, wgrid);
        p2_kernel<<<nbk, 1024, 0, stream>>>(bcursor, bpack, rp, csr,
                                            n_nodes, n_edges, nbk);

        // ---- shift chain back-to-back (L2-hot producer->consumer) ----
        pull_bf16_kernel<<<pgrid, tb, 0, stream>>>(xb, Ab, rp, csr, n_nodes);
        pull_bf16_kernel<<<pgrid, tb, 0, stream>>>(Ab, Bb, rp, csr, n_nodes);
        pull_bf16_kernel<<<pgrid, tb, 0, stream>>>(Bb, Cb, rp, csr, n_nodes);

        // ---- tap phase: single MFMA GEMM  y = Xcat @ Wcat^T + bsum ----
        mfma_tap_kernel<<<mgrid, tb, 0, stream>>>(xb, Ab, Bb, Cb, Wb, b, y, n_tiles);
    } else {
        // ---- fallback: atomic push path (f32) ----
        float* A = (float*)d_ws;
        float* B = A + bufElems;
        size_t bufBytes = bufElems * sizeof(float);
        int sgrid = (n_edges * 16 + 255) / 256;
        hipMemsetAsync(A, 0, bufBytes, stream);
        hipMemsetAsync(B, 0, bufBytes, stream);
        tap_kernel<<<tg, tb, 0, stream>>>(x, W, b, y, n_nodes, 1);
        scatter_kernel<<<sgrid, tb, 0, stream>>>(x, A, src, dst, n_edges);
        tap_kernel<<<tg, tb, 0, stream>>>(A, W + D * D, b + D, y, n_nodes, 0);
        scatter_kernel<<<sgrid, tb, 0, stream>>>(A, B, src, dst, n_edges);
        hipMemsetAsync(A, 0, bufBytes, stream);
        tap_kernel<<<tg, tb, 0, stream>>>(B, W + 2 * D * D, b + 2 * D, y, n_nodes, 0);
        scatter_kernel<<<sgrid, tb, 0, stream>>>(B, A, src, dst, n_edges);
        tap_kernel<<<tg, tb, 0, stream>>>(A, W + 3 * D * D, b + 3 * D, y, n_nodes, 0);
    }
}